// Round 1
// baseline (959.768 us; speedup 1.0000x reference)
//
#include <hip/hip_runtime.h>
#include <hip/hip_bf16.h>

#define N_NODES 100000
#define N_EDGES 800000
#define N_GRAPHS 16
#define NFEAT 128
#define NHID 128
#define NCLASS 2

#define SCAN_CHUNK 2048
#define NCHUNK ((N_NODES + SCAN_CHUNK - 1) / SCAN_CHUNK)  // 49
#define CONV2_BLOCKS 256
#define CONV2_TPB 1024
#define N_ITEMS (N_EDGES + N_NODES)  // edges + self-loop/pool items

// ---------------- utility ----------------
__global__ void k_zero2(int* __restrict__ a, int* __restrict__ b) {
  int i = blockIdx.x * blockDim.x + threadIdx.x;
  if (i < N_NODES) { a[i] = 0; b[i] = 0; }
}

// in-degree from edge targets (self-loops handled analytically later)
__global__ void k_deg(const int* __restrict__ ei, int* __restrict__ deg) {
  int e = blockIdx.x * blockDim.x + threadIdx.x;
  if (e < N_EDGES) atomicAdd(&deg[ei[N_EDGES + e]], 1);
}

__global__ void k_dinv(const int* __restrict__ deg, float* __restrict__ dinv) {
  int i = blockIdx.x * blockDim.x + threadIdx.x;
  if (i < N_NODES) dinv[i] = rsqrtf((float)deg[i] + 1.0f);  // +1 = self loop
}

// ---------------- exclusive scan of deg -> offsets ----------------
__global__ void k_scan1(const int* __restrict__ deg, int* __restrict__ csum) {
  __shared__ int lds[256];
  int b = blockIdx.x, t = threadIdx.x;
  int base = b * SCAN_CHUNK + t * 8;
  int s = 0;
#pragma unroll
  for (int k = 0; k < 8; ++k) {
    int i = base + k;
    s += (i < N_NODES) ? deg[i] : 0;
  }
  lds[t] = s;
  __syncthreads();
  for (int off = 128; off > 0; off >>= 1) {
    if (t < off) lds[t] += lds[t + off];
    __syncthreads();
  }
  if (t == 0) csum[b] = lds[0];
}

__global__ void k_scan2(const int* __restrict__ csum, int* __restrict__ coff) {
  if (threadIdx.x == 0) {
    int run = 0;
    for (int i = 0; i < NCHUNK; ++i) { coff[i] = run; run += csum[i]; }
  }
}

__global__ void k_scan3(const int* __restrict__ deg, const int* __restrict__ coff,
                        int* __restrict__ offsets) {
  __shared__ int lds[256];
  int b = blockIdx.x, t = threadIdx.x;
  int base = b * SCAN_CHUNK + t * 8;
  int v[8];
  int s = 0;
#pragma unroll
  for (int k = 0; k < 8; ++k) {
    int i = base + k;
    v[k] = (i < N_NODES) ? deg[i] : 0;
    s += v[k];
  }
  lds[t] = s;
  __syncthreads();
  int total = s;
  for (int off = 1; off < 256; off <<= 1) {
    int x = (t >= off) ? lds[t - off] : 0;
    __syncthreads();
    lds[t] += x;
    __syncthreads();
  }
  int run = lds[t] - total + coff[b];  // exclusive prefix for this thread
#pragma unroll
  for (int k = 0; k < 8; ++k) {
    int i = base + k;
    if (i < N_NODES) offsets[i] = run;
    run += v[k];
  }
}

__global__ void k_fill(const int* __restrict__ ei, const int* __restrict__ offsets,
                       int* __restrict__ cursor, int* __restrict__ csr_row) {
  int e = blockIdx.x * blockDim.x + threadIdx.x;
  if (e < N_EDGES) {
    int r = ei[e];
    int c = ei[N_EDGES + e];
    int p = atomicAdd(&cursor[c], 1);
    csr_row[offsets[c] + p] = r;
  }
}

// ---------------- xw = x @ W1  (fp32 vector GEMM, W1 in LDS) ----------------
__global__ __launch_bounds__(256) void k_gemm1(const float* __restrict__ x,
                                               const float* __restrict__ W1,
                                               float* __restrict__ xw) {
  __shared__ float Wl[128 * 128];
  int t = threadIdx.x;
  for (int i = t; i < 4096; i += 256)
    ((float4*)Wl)[i] = ((const float4*)W1)[i];
  __syncthreads();

  int cg = t >> 5;  // 0..7 col group of 16 (wave-uniform-ish: 2 per wave -> bcast LDS reads)
  int rq = t & 31;  // 0..31 row pair
  int r0 = blockIdx.x * 64 + rq * 2;
  int r1 = r0 + 1;
  bool v0 = r0 < N_NODES, v1 = r1 < N_NODES;
  float acc0[16], acc1[16];
#pragma unroll
  for (int i = 0; i < 16; ++i) { acc0[i] = 0.f; acc1[i] = 0.f; }
  const float* xr0 = x + (size_t)r0 * 128;
  const float* xr1 = x + (size_t)r1 * 128;
  for (int k = 0; k < 128; k += 4) {
    float4 a0 = v0 ? *(const float4*)(xr0 + k) : make_float4(0.f, 0.f, 0.f, 0.f);
    float4 a1 = v1 ? *(const float4*)(xr1 + k) : make_float4(0.f, 0.f, 0.f, 0.f);
#pragma unroll
    for (int kk = 0; kk < 4; ++kk) {
      const float* wr = &Wl[(k + kk) * 128 + cg * 16];
      float av0 = (&a0.x)[kk];
      float av1 = (&a1.x)[kk];
#pragma unroll
      for (int j = 0; j < 16; ++j) {
        float wv = wr[j];
        acc0[j] += av0 * wv;
        acc1[j] += av1 * wv;
      }
    }
  }
  if (v0) {
    float4* o = (float4*)(xw + (size_t)r0 * 128 + cg * 16);
#pragma unroll
    for (int q = 0; q < 4; ++q)
      o[q] = make_float4(acc0[q * 4], acc0[q * 4 + 1], acc0[q * 4 + 2], acc0[q * 4 + 3]);
  }
  if (v1) {
    float4* o = (float4*)(xw + (size_t)r1 * 128 + cg * 16);
#pragma unroll
    for (int q = 0; q < 4; ++q)
      o[q] = make_float4(acc1[q * 4], acc1[q * 4 + 1], acc1[q * 4 + 2], acc1[q * 4 + 3]);
  }
}

// ---------------- conv1: per-node CSR gather, h = relu(A xw + b1) ----------------
__global__ __launch_bounds__(256) void k_conv1(const float* __restrict__ xw,
                                               const int* __restrict__ csr_row,
                                               const int* __restrict__ offsets,
                                               const int* __restrict__ deg,
                                               const float* __restrict__ dinv,
                                               const float* __restrict__ b1,
                                               float* __restrict__ h) {
  int lane = threadIdx.x & 63;
  int c = blockIdx.x * 4 + (threadIdx.x >> 6);  // one wave per node
  if (c >= N_NODES) return;
  float dc = dinv[c];
  const float2* base = (const float2*)xw;
  float2 self = base[(size_t)c * 64 + lane];
  float acc0 = self.x * dc * dc;  // self loop, norm = dinv[c]^2
  float acc1 = self.y * dc * dc;
  int st = offsets[c], cnt = deg[c];
#pragma unroll 2
  for (int s = 0; s < cnt; ++s) {
    int r = csr_row[st + s];
    float w = dinv[r] * dc;
    float2 xv = base[(size_t)r * 64 + lane];
    acc0 += xv.x * w;
    acc1 += xv.y * w;
  }
  float2 bb = ((const float2*)b1)[lane];
  float2 out;
  out.x = fmaxf(acc0 + bb.x, 0.f);
  out.y = fmaxf(acc1 + bb.y, 0.f);
  ((float2*)h)[(size_t)c * 64 + lane] = out;
}

// ---- conv2 fused with pooling: s[g] += norm_e * h[row_e] over edges+selfloops ----
__global__ __launch_bounds__(CONV2_TPB) void k_conv2(const float* __restrict__ h,
                                                     const int* __restrict__ ei,
                                                     const int* __restrict__ batch,
                                                     const float* __restrict__ dinv,
                                                     float* __restrict__ partials) {
  __shared__ float sacc[N_GRAPHS * 128];
  int t = threadIdx.x;
  for (int i = t; i < N_GRAPHS * 128; i += CONV2_TPB) sacc[i] = 0.f;
  __syncthreads();

  int lane = t & 63;
  int wave = blockIdx.x * (CONV2_TPB / 64) + (t >> 6);
  const int nwaves = CONV2_BLOCKS * (CONV2_TPB / 64);
  const int per = (N_ITEMS + nwaves - 1) / nwaves;
  int start = wave * per;
  int end = min(start + per, N_ITEMS);

  for (int base2 = start; base2 < end; base2 += 64) {
    int i = base2 + lane;
    int r = 0, g = 0;
    float w = 0.f;
    if (i < end) {
      if (i < N_EDGES) {
        r = ei[i];
        int c = ei[N_EDGES + i];
        g = batch[c];
        w = dinv[r] * dinv[c];
      } else {
        int nn = i - N_EDGES;  // self loop of node nn (also the pooling sum item)
        r = nn;
        g = batch[nn];
        float d = dinv[nn];
        w = d * d;
      }
    }
    int m = min(64, end - base2);
    for (int j = 0; j < m; ++j) {
      int rj = __shfl(r, j, 64);
      int gj = __shfl(g, j, 64);
      float wj = __shfl(w, j, 64);
      float2 hv = ((const float2*)h)[(size_t)rj * 64 + lane];
      atomicAdd(&sacc[gj * 128 + lane * 2], hv.x * wj);
      atomicAdd(&sacc[gj * 128 + lane * 2 + 1], hv.y * wj);
    }
  }
  __syncthreads();
  for (int i = t; i < N_GRAPHS * 128; i += CONV2_TPB)
    partials[(size_t)blockIdx.x * (N_GRAPHS * 128) + i] = sacc[i];
}

__global__ void k_reduce(const float* __restrict__ partials, float* __restrict__ sglob) {
  int i = blockIdx.x * blockDim.x + threadIdx.x;
  if (i < N_GRAPHS * 128) {
    float s = 0.f;
    for (int b = 0; b < CONV2_BLOCKS; ++b) s += partials[(size_t)b * (N_GRAPHS * 128) + i];
    sglob[i] = s;
  }
}

// ---------------- final: counts (binary search), s@W2, mean, log_softmax ----------------
__global__ void k_final(const float* __restrict__ sglob, const int* __restrict__ batch,
                        const float* __restrict__ W2, const float* __restrict__ b2,
                        float* __restrict__ out) {
  __shared__ int bnd[N_GRAPHS + 1];
  int t = threadIdx.x;
  if (t <= N_GRAPHS) {
    if (t == N_GRAPHS) {
      bnd[t] = N_NODES;
    } else if (t == 0) {
      bnd[t] = 0;
    } else {
      int lo = 0, hi = N_NODES;  // first idx with batch[idx] >= t (batch is sorted)
      while (lo < hi) {
        int mid = (lo + hi) >> 1;
        if (batch[mid] < t) lo = mid + 1; else hi = mid;
      }
      bnd[t] = lo;
    }
  }
  __syncthreads();
  if (t < N_GRAPHS) {
    float cnt = fmaxf((float)(bnd[t + 1] - bnd[t]), 1.0f);
    float p0 = 0.f, p1 = 0.f;
    const float* sg = sglob + t * 128;
    for (int f = 0; f < 128; ++f) {
      float sv = sg[f];
      p0 += sv * W2[f * 2 + 0];
      p1 += sv * W2[f * 2 + 1];
    }
    // pooled = sum/cnt; (sum of h2 over graph) = s@W2 + cnt*b2  =>  pooled = s@W2/cnt + b2
    p0 = p0 / cnt + b2[0];
    p1 = p1 / cnt + b2[1];
    float m = fmaxf(p0, p1);
    float lse = m + logf(expf(p0 - m) + expf(p1 - m));
    out[t * 2 + 0] = p0 - lse;
    out[t * 2 + 1] = p1 - lse;
  }
}

// ---------------- launch ----------------
static inline size_t align256(size_t x) { return (x + 255) & ~(size_t)255; }

extern "C" void kernel_launch(void* const* d_in, const int* in_sizes, int n_in,
                              void* d_out, int out_size, void* d_ws, size_t ws_size,
                              hipStream_t stream) {
  (void)in_sizes; (void)n_in; (void)out_size;
  const float* x  = (const float*)d_in[0];
  const int*   ei = (const int*)d_in[1];   // [2][E]
  const int*   batch = (const int*)d_in[2];
  const float* W1 = (const float*)d_in[3];
  const float* b1 = (const float*)d_in[4];
  const float* W2 = (const float*)d_in[5];
  const float* b2 = (const float*)d_in[6];
  float* out = (float*)d_out;

  char* w = (char*)d_ws;
  size_t off = 0;
  float* xw = (float*)(w + off);      off = align256(off + (size_t)N_NODES * NHID * 4);
  float* h  = (float*)(w + off);      off = align256(off + (size_t)N_NODES * NHID * 4);
  float* partials = (float*)(w + off); off = align256(off + (size_t)CONV2_BLOCKS * N_GRAPHS * 128 * 4);
  float* sglob = (float*)(w + off);   off = align256(off + (size_t)N_GRAPHS * 128 * 4);
  float* dinv = (float*)(w + off);    off = align256(off + (size_t)N_NODES * 4);
  int* deg = (int*)(w + off);         off = align256(off + (size_t)N_NODES * 4);
  int* cursor = (int*)(w + off);      off = align256(off + (size_t)N_NODES * 4);
  int* offsets = (int*)(w + off);     off = align256(off + (size_t)N_NODES * 4);
  int* csr_row = (int*)(w + off);     off = align256(off + (size_t)N_EDGES * 4);
  int* csum = (int*)(w + off);        off = align256(off + (size_t)NCHUNK * 4);
  int* coff = (int*)(w + off);        off = align256(off + (size_t)NCHUNK * 4);
  (void)ws_size;  // needs ~110 MB

  k_zero2<<<(N_NODES + 255) / 256, 256, 0, stream>>>(deg, cursor);
  k_deg<<<(N_EDGES + 255) / 256, 256, 0, stream>>>(ei, deg);
  k_dinv<<<(N_NODES + 255) / 256, 256, 0, stream>>>(deg, dinv);
  k_scan1<<<NCHUNK, 256, 0, stream>>>(deg, csum);
  k_scan2<<<1, 64, 0, stream>>>(csum, coff);
  k_scan3<<<NCHUNK, 256, 0, stream>>>(deg, coff, offsets);
  k_fill<<<(N_EDGES + 255) / 256, 256, 0, stream>>>(ei, offsets, cursor, csr_row);
  k_gemm1<<<(N_NODES + 63) / 64, 256, 0, stream>>>(x, W1, xw);
  k_conv1<<<(N_NODES + 3) / 4, 256, 0, stream>>>(xw, csr_row, offsets, deg, dinv, b1, h);
  k_conv2<<<CONV2_BLOCKS, CONV2_TPB, 0, stream>>>(h, ei, batch, dinv, partials);
  k_reduce<<<8, 256, 0, stream>>>(partials, sglob);
  k_final<<<1, 64, 0, stream>>>(sglob, batch, W2, b2, out);
}

// Round 2
// 433.901 us; speedup vs baseline: 2.2120x; 2.2120x over previous
//
#include <hip/hip_runtime.h>
#include <hip/hip_bf16.h>

#define N_NODES 100000
#define N_EDGES 800000
#define N_GRAPHS 16
#define NFEAT 128
#define NHID 128
#define NCLASS 2

#define SCAN_CHUNK 2048
#define NCHUNK ((N_NODES + SCAN_CHUNK - 1) / SCAN_CHUNK)  // 49

#define SUM_ROWS 256
#define SUM_NB ((N_NODES + SUM_ROWS - 1) / SUM_ROWS)  // 391

// ---------------- utility ----------------
__global__ void k_zero2(int* __restrict__ a, int* __restrict__ b) {
  int i = blockIdx.x * blockDim.x + threadIdx.x;
  if (i < N_NODES) { a[i] = 0; b[i] = 0; }
}

// in-degree from edge targets (self-loop handled as +1 in dinv)
__global__ void k_deg(const int* __restrict__ ei, int* __restrict__ deg) {
  int e = blockIdx.x * blockDim.x + threadIdx.x;
  if (e < N_EDGES) atomicAdd(&deg[ei[N_EDGES + e]], 1);
}

__global__ void k_dinv(const int* __restrict__ deg, float* __restrict__ dinv) {
  int i = blockIdx.x * blockDim.x + threadIdx.x;
  if (i < N_NODES) dinv[i] = rsqrtf((float)deg[i] + 1.0f);
}

// ---------------- exclusive scan of deg -> offsets ----------------
__global__ void k_scan1(const int* __restrict__ deg, int* __restrict__ csum) {
  __shared__ int lds[256];
  int b = blockIdx.x, t = threadIdx.x;
  int base = b * SCAN_CHUNK + t * 8;
  int s = 0;
#pragma unroll
  for (int k = 0; k < 8; ++k) {
    int i = base + k;
    s += (i < N_NODES) ? deg[i] : 0;
  }
  lds[t] = s;
  __syncthreads();
  for (int off = 128; off > 0; off >>= 1) {
    if (t < off) lds[t] += lds[t + off];
    __syncthreads();
  }
  if (t == 0) csum[b] = lds[0];
}

__global__ void k_scan2(const int* __restrict__ csum, int* __restrict__ coff) {
  if (threadIdx.x == 0) {
    int run = 0;
    for (int i = 0; i < NCHUNK; ++i) { coff[i] = run; run += csum[i]; }
  }
}

__global__ void k_scan3(const int* __restrict__ deg, const int* __restrict__ coff,
                        int* __restrict__ offsets) {
  __shared__ int lds[256];
  int b = blockIdx.x, t = threadIdx.x;
  int base = b * SCAN_CHUNK + t * 8;
  int v[8];
  int s = 0;
#pragma unroll
  for (int k = 0; k < 8; ++k) {
    int i = base + k;
    v[k] = (i < N_NODES) ? deg[i] : 0;
    s += v[k];
  }
  lds[t] = s;
  __syncthreads();
  int total = s;
  for (int off = 1; off < 256; off <<= 1) {
    int x = (t >= off) ? lds[t - off] : 0;
    __syncthreads();
    lds[t] += x;
    __syncthreads();
  }
  int run = lds[t] - total + coff[b];
#pragma unroll
  for (int k = 0; k < 8; ++k) {
    int i = base + k;
    if (i < N_NODES) offsets[i] = run;
    run += v[k];
  }
}

__global__ void k_fill(const int* __restrict__ ei, const int* __restrict__ offsets,
                       int* __restrict__ cursor, int* __restrict__ csr_row) {
  int e = blockIdx.x * blockDim.x + threadIdx.x;
  if (e < N_EDGES) {
    int r = ei[e];
    int c = ei[N_EDGES + e];
    int p = atomicAdd(&cursor[c], 1);
    csr_row[offsets[c] + p] = r;
  }
}

// ------- xw' = (x @ W1) * dinv[row]  (fp32 vector GEMM, W1 in LDS) -------
__global__ __launch_bounds__(256) void k_gemm1(const float* __restrict__ x,
                                               const float* __restrict__ W1,
                                               const float* __restrict__ dinv,
                                               float* __restrict__ xw) {
  __shared__ float Wl[128 * 128];
  int t = threadIdx.x;
  for (int i = t; i < 4096; i += 256)
    ((float4*)Wl)[i] = ((const float4*)W1)[i];
  __syncthreads();

  int cg = t >> 5;  // col group of 16
  int rq = t & 31;  // row pair
  int r0 = blockIdx.x * 64 + rq * 2;
  int r1 = r0 + 1;
  bool v0 = r0 < N_NODES, v1 = r1 < N_NODES;
  float acc0[16], acc1[16];
#pragma unroll
  for (int i = 0; i < 16; ++i) { acc0[i] = 0.f; acc1[i] = 0.f; }
  const float* xr0 = x + (size_t)r0 * 128;
  const float* xr1 = x + (size_t)r1 * 128;
  for (int k = 0; k < 128; k += 4) {
    float4 a0 = v0 ? *(const float4*)(xr0 + k) : make_float4(0.f, 0.f, 0.f, 0.f);
    float4 a1 = v1 ? *(const float4*)(xr1 + k) : make_float4(0.f, 0.f, 0.f, 0.f);
#pragma unroll
    for (int kk = 0; kk < 4; ++kk) {
      const float* wr = &Wl[(k + kk) * 128 + cg * 16];
      float av0 = (&a0.x)[kk];
      float av1 = (&a1.x)[kk];
#pragma unroll
      for (int j = 0; j < 16; ++j) {
        float wv = wr[j];
        acc0[j] += av0 * wv;
        acc1[j] += av1 * wv;
      }
    }
  }
  if (v0) {
    float d0 = dinv[r0];
    float4* o = (float4*)(xw + (size_t)r0 * 128 + cg * 16);
#pragma unroll
    for (int q = 0; q < 4; ++q)
      o[q] = make_float4(acc0[q * 4] * d0, acc0[q * 4 + 1] * d0, acc0[q * 4 + 2] * d0,
                         acc0[q * 4 + 3] * d0);
  }
  if (v1) {
    float d1 = dinv[r1];
    float4* o = (float4*)(xw + (size_t)r1 * 128 + cg * 16);
#pragma unroll
    for (int q = 0; q < 4; ++q)
      o[q] = make_float4(acc1[q * 4] * d1, acc1[q * 4 + 1] * d1, acc1[q * 4 + 2] * d1,
                         acc1[q * 4 + 3] * d1);
  }
}

// ----- conv1: per-node CSR gather of pre-scaled xw', h = relu(dc*Σ + b1) -----
__global__ __launch_bounds__(256) void k_conv1(const float* __restrict__ xw,
                                               const int* __restrict__ csr_row,
                                               const int* __restrict__ offsets,
                                               const int* __restrict__ deg,
                                               const float* __restrict__ dinv,
                                               const float* __restrict__ b1,
                                               float* __restrict__ h) {
  int lane = threadIdx.x & 63;
  int c = blockIdx.x * 4 + (threadIdx.x >> 6);  // one wave per node
  if (c >= N_NODES) return;
  float dc = dinv[c];
  const float2* base = (const float2*)xw;
  float2 self = base[(size_t)c * 64 + lane];  // = xw[c]*dinv[c]
  float acc0 = self.x;
  float acc1 = self.y;
  int st = offsets[c], cnt = deg[c];
  int s = 0;
  for (; s + 4 <= cnt; s += 4) {  // 4 independent gathers in flight
    int r0 = csr_row[st + s + 0];
    int r1 = csr_row[st + s + 1];
    int r2 = csr_row[st + s + 2];
    int r3 = csr_row[st + s + 3];
    float2 v0 = base[(size_t)r0 * 64 + lane];
    float2 v1 = base[(size_t)r1 * 64 + lane];
    float2 v2 = base[(size_t)r2 * 64 + lane];
    float2 v3 = base[(size_t)r3 * 64 + lane];
    acc0 += (v0.x + v1.x) + (v2.x + v3.x);
    acc1 += (v0.y + v1.y) + (v2.y + v3.y);
  }
  for (; s < cnt; ++s) {
    int r = csr_row[st + s];
    float2 v = base[(size_t)r * 64 + lane];
    acc0 += v.x;
    acc1 += v.y;
  }
  float2 bb = ((const float2*)b1)[lane];
  float2 out;
  out.x = fmaxf(acc0 * dc + bb.x, 0.f);
  out.y = fmaxf(acc1 * dc + bb.y, 0.f);
  ((float2*)h)[(size_t)c * 64 + lane] = out;
}

// ----- coef[r][g] = Σ_{e from r, batch[col]=g} dinv[r]dinv[c]  (+self) -----
__global__ void k_coef_init(const int* __restrict__ batch, const float* __restrict__ dinv,
                            float* __restrict__ coef) {
  int i = blockIdx.x * blockDim.x + threadIdx.x;  // node*16+g
  if (i < N_NODES * N_GRAPHS) {
    int n = i >> 4, g = i & 15;
    float d = dinv[n];
    coef[i] = (g == batch[n]) ? d * d : 0.f;
  }
}

__global__ void k_coef_edge(const int* __restrict__ ei, const int* __restrict__ batch,
                            const float* __restrict__ dinv, float* __restrict__ coef) {
  int e = blockIdx.x * blockDim.x + threadIdx.x;
  if (e < N_EDGES) {
    int r = ei[e];
    int c = ei[N_EDGES + e];
    int g = batch[c];
    atomicAdd(&coef[r * N_GRAPHS + g], dinv[r] * dinv[c]);
  }
}

// ----- s[g][f] = Σ_r coef[r][g]*h[r][f]  (streaming; coef staged in LDS) -----
__global__ __launch_bounds__(256) void k_sum(const float* __restrict__ h,
                                             const float* __restrict__ coef,
                                             float* __restrict__ partials) {
  __shared__ float lds[8192];  // phase1: coef tile (16KB); phase2: wave partials (32KB)
  int t = threadIdx.x;
  int base = blockIdx.x * SUM_ROWS;

  // stage coef[base .. base+255][16] -> lds[0..4095]
  for (int i = t; i < SUM_ROWS * 16 / 4; i += 256) {
    int gidx = base * 16 / 4 + i;
    float4 v = (gidx * 4 < N_NODES * 16) ? ((const float4*)coef)[gidx]
                                         : make_float4(0.f, 0.f, 0.f, 0.f);
    ((float4*)lds)[i] = v;
  }
  __syncthreads();

  int lane = t & 63;
  int q = t >> 6;  // wave id 0..3
  float2 acc[16];
#pragma unroll
  for (int g = 0; g < 16; ++g) acc[g] = make_float2(0.f, 0.f);

  const float2* h2 = (const float2*)h;
  for (int k = 0; k < SUM_ROWS / 4; ++k) {
    int lr = q + 4 * k;       // local row
    int r = base + lr;        // global row
    float2 hv = (r < N_NODES) ? h2[(size_t)r * 64 + lane] : make_float2(0.f, 0.f);
    const float4* cb = (const float4*)&lds[lr * 16];
    float4 c0 = cb[0], c1 = cb[1], c2 = cb[2], c3 = cb[3];
    acc[0].x += c0.x * hv.x;  acc[0].y += c0.x * hv.y;
    acc[1].x += c0.y * hv.x;  acc[1].y += c0.y * hv.y;
    acc[2].x += c0.z * hv.x;  acc[2].y += c0.z * hv.y;
    acc[3].x += c0.w * hv.x;  acc[3].y += c0.w * hv.y;
    acc[4].x += c1.x * hv.x;  acc[4].y += c1.x * hv.y;
    acc[5].x += c1.y * hv.x;  acc[5].y += c1.y * hv.y;
    acc[6].x += c1.z * hv.x;  acc[6].y += c1.z * hv.y;
    acc[7].x += c1.w * hv.x;  acc[7].y += c1.w * hv.y;
    acc[8].x += c2.x * hv.x;  acc[8].y += c2.x * hv.y;
    acc[9].x += c2.y * hv.x;  acc[9].y += c2.y * hv.y;
    acc[10].x += c2.z * hv.x; acc[10].y += c2.z * hv.y;
    acc[11].x += c2.w * hv.x; acc[11].y += c2.w * hv.y;
    acc[12].x += c3.x * hv.x; acc[12].y += c3.x * hv.y;
    acc[13].x += c3.y * hv.x; acc[13].y += c3.y * hv.y;
    acc[14].x += c3.z * hv.x; acc[14].y += c3.z * hv.y;
    acc[15].x += c3.w * hv.x; acc[15].y += c3.w * hv.y;
  }
  __syncthreads();  // done with coef tile; reuse lds as float2 red[4][16][64]
  float2* red = (float2*)lds;
#pragma unroll
  for (int g = 0; g < 16; ++g) red[(q * 16 + g) * 64 + lane] = acc[g];
  __syncthreads();
#pragma unroll
  for (int ii = 0; ii < 4; ++ii) {
    int i = t + ii * 256;        // item in [0,1024): g = i>>6, fp = i&63
    int g = i >> 6, fp = i & 63;
    float2 s = red[(0 * 16 + g) * 64 + fp];
    float2 s1 = red[(1 * 16 + g) * 64 + fp];
    float2 s2 = red[(2 * 16 + g) * 64 + fp];
    float2 s3 = red[(3 * 16 + g) * 64 + fp];
    s.x += s1.x + s2.x + s3.x;
    s.y += s1.y + s2.y + s3.y;
    ((float2*)partials)[(size_t)blockIdx.x * 1024 + g * 64 + fp] = s;
  }
}

__global__ void k_reduce(const float* __restrict__ partials, float* __restrict__ sglob) {
  int i = blockIdx.x * blockDim.x + threadIdx.x;
  if (i < N_GRAPHS * 128) {
    float s = 0.f;
    for (int b = 0; b < SUM_NB; ++b) s += partials[(size_t)b * (N_GRAPHS * 128) + i];
    sglob[i] = s;
  }
}

// ---------------- final: counts, s@W2, mean, log_softmax ----------------
__global__ void k_final(const float* __restrict__ sglob, const int* __restrict__ batch,
                        const float* __restrict__ W2, const float* __restrict__ b2,
                        float* __restrict__ out) {
  __shared__ int bnd[N_GRAPHS + 1];
  int t = threadIdx.x;
  if (t <= N_GRAPHS) {
    if (t == N_GRAPHS) {
      bnd[t] = N_NODES;
    } else if (t == 0) {
      bnd[t] = 0;
    } else {
      int lo = 0, hi = N_NODES;
      while (lo < hi) {
        int mid = (lo + hi) >> 1;
        if (batch[mid] < t) lo = mid + 1; else hi = mid;
      }
      bnd[t] = lo;
    }
  }
  __syncthreads();
  if (t < N_GRAPHS) {
    float cnt = fmaxf((float)(bnd[t + 1] - bnd[t]), 1.0f);
    float p0 = 0.f, p1 = 0.f;
    const float* sg = sglob + t * 128;
    for (int f = 0; f < 128; ++f) {
      float sv = sg[f];
      p0 += sv * W2[f * 2 + 0];
      p1 += sv * W2[f * 2 + 1];
    }
    p0 = p0 / cnt + b2[0];
    p1 = p1 / cnt + b2[1];
    float m = fmaxf(p0, p1);
    float lse = m + logf(expf(p0 - m) + expf(p1 - m));
    out[t * 2 + 0] = p0 - lse;
    out[t * 2 + 1] = p1 - lse;
  }
}

// ---------------- launch ----------------
static inline size_t align256(size_t x) { return (x + 255) & ~(size_t)255; }

extern "C" void kernel_launch(void* const* d_in, const int* in_sizes, int n_in,
                              void* d_out, int out_size, void* d_ws, size_t ws_size,
                              hipStream_t stream) {
  (void)in_sizes; (void)n_in; (void)out_size; (void)ws_size;
  const float* x  = (const float*)d_in[0];
  const int*   ei = (const int*)d_in[1];   // [2][E]
  const int*   batch = (const int*)d_in[2];
  const float* W1 = (const float*)d_in[3];
  const float* b1 = (const float*)d_in[4];
  const float* W2 = (const float*)d_in[5];
  const float* b2 = (const float*)d_in[6];
  float* out = (float*)d_out;

  char* w = (char*)d_ws;
  size_t off = 0;
  float* xw = (float*)(w + off);       off = align256(off + (size_t)N_NODES * NHID * 4);
  float* coef = xw;                    // alias: coef written after conv1 (xw dead)
  float* h  = (float*)(w + off);       off = align256(off + (size_t)N_NODES * NHID * 4);
  int* csr_row = (int*)(w + off);      // alias with partials (partials used after conv1)
  float* partials = (float*)(w + off);
  size_t shared_sz = (size_t)SUM_NB * N_GRAPHS * 128 * 4;  // 3.2MB > csr 3.2MB
  if ((size_t)N_EDGES * 4 > shared_sz) shared_sz = (size_t)N_EDGES * 4;
  off = align256(off + shared_sz);
  float* sglob = (float*)(w + off);    off = align256(off + (size_t)N_GRAPHS * 128 * 4);
  float* dinv = (float*)(w + off);     off = align256(off + (size_t)N_NODES * 4);
  int* deg = (int*)(w + off);          off = align256(off + (size_t)N_NODES * 4);
  int* cursor = (int*)(w + off);       off = align256(off + (size_t)N_NODES * 4);
  int* offsets = (int*)(w + off);      off = align256(off + (size_t)N_NODES * 4);
  int* csum = (int*)(w + off);         off = align256(off + (size_t)NCHUNK * 4);
  int* coff = (int*)(w + off);         off = align256(off + (size_t)NCHUNK * 4);

  k_zero2<<<(N_NODES + 255) / 256, 256, 0, stream>>>(deg, cursor);
  k_deg<<<(N_EDGES + 255) / 256, 256, 0, stream>>>(ei, deg);
  k_dinv<<<(N_NODES + 255) / 256, 256, 0, stream>>>(deg, dinv);
  k_scan1<<<NCHUNK, 256, 0, stream>>>(deg, csum);
  k_scan2<<<1, 64, 0, stream>>>(csum, coff);
  k_scan3<<<NCHUNK, 256, 0, stream>>>(deg, coff, offsets);
  k_fill<<<(N_EDGES + 255) / 256, 256, 0, stream>>>(ei, offsets, cursor, csr_row);
  k_gemm1<<<(N_NODES + 63) / 64, 256, 0, stream>>>(x, W1, dinv, xw);
  k_conv1<<<(N_NODES + 3) / 4, 256, 0, stream>>>(xw, csr_row, offsets, deg, dinv, b1, h);
  // xw dead from here; coef aliases it
  k_coef_init<<<(N_NODES * N_GRAPHS + 255) / 256, 256, 0, stream>>>(batch, dinv, coef);
  k_coef_edge<<<(N_EDGES + 255) / 256, 256, 0, stream>>>(ei, batch, dinv, coef);
  k_sum<<<SUM_NB, 256, 0, stream>>>(h, coef, partials);
  k_reduce<<<8, 256, 0, stream>>>(partials, sglob);
  k_final<<<1, 64, 0, stream>>>(sglob, batch, W2, b2, out);
}

// Round 3
// 430.994 us; speedup vs baseline: 2.2269x; 1.0067x over previous
//
#include <hip/hip_runtime.h>
#include <hip/hip_bf16.h>

#define N_NODES 100000
#define N_EDGES 800000
#define N_GRAPHS 16
#define NFEAT 128
#define NHID 128
#define NCLASS 2

#define SCAN_CHUNK 2048
#define NCHUNK ((N_NODES + SCAN_CHUNK - 1) / SCAN_CHUNK)  // 49

#define SUM_ROWS 256
#define SUM_NB ((N_NODES + SUM_ROWS - 1) / SUM_ROWS)  // 391

// ---------------- utility ----------------
__global__ void k_zero2(int* __restrict__ a, int* __restrict__ b) {
  int i = blockIdx.x * blockDim.x + threadIdx.x;
  if (i < N_NODES) { a[i] = 0; b[i] = 0; }
}

// in-degree from edge targets (self-loop handled as +1 in dinv)
__global__ void k_deg(const int* __restrict__ ei, int* __restrict__ deg) {
  int e = blockIdx.x * blockDim.x + threadIdx.x;
  if (e < N_EDGES) atomicAdd(&deg[ei[N_EDGES + e]], 1);
}

// ---------------- exclusive scan of deg -> offsets (+ dinv fused) ----------------
__global__ void k_scan1(const int* __restrict__ deg, int* __restrict__ csum,
                        float* __restrict__ dinv) {
  __shared__ int lds[256];
  int b = blockIdx.x, t = threadIdx.x;
  int base = b * SCAN_CHUNK + t * 8;
  int s = 0;
#pragma unroll
  for (int k = 0; k < 8; ++k) {
    int i = base + k;
    int d = (i < N_NODES) ? deg[i] : 0;
    if (i < N_NODES) dinv[i] = rsqrtf((float)d + 1.0f);
    s += d;
  }
  lds[t] = s;
  __syncthreads();
  for (int off = 128; off > 0; off >>= 1) {
    if (t < off) lds[t] += lds[t + off];
    __syncthreads();
  }
  if (t == 0) csum[b] = lds[0];
}

__global__ void k_scan2(const int* __restrict__ csum, int* __restrict__ coff) {
  if (threadIdx.x == 0) {
    int run = 0;
    for (int i = 0; i < NCHUNK; ++i) { coff[i] = run; run += csum[i]; }
  }
}

__global__ void k_scan3(const int* __restrict__ deg, const int* __restrict__ coff,
                        int* __restrict__ offsets) {
  __shared__ int lds[256];
  int b = blockIdx.x, t = threadIdx.x;
  int base = b * SCAN_CHUNK + t * 8;
  int v[8];
  int s = 0;
#pragma unroll
  for (int k = 0; k < 8; ++k) {
    int i = base + k;
    v[k] = (i < N_NODES) ? deg[i] : 0;
    s += v[k];
  }
  lds[t] = s;
  __syncthreads();
  int total = s;
  for (int off = 1; off < 256; off <<= 1) {
    int x = (t >= off) ? lds[t - off] : 0;
    __syncthreads();
    lds[t] += x;
    __syncthreads();
  }
  int run = lds[t] - total + coff[b];
#pragma unroll
  for (int k = 0; k < 8; ++k) {
    int i = base + k;
    if (i < N_NODES) offsets[i] = run;
    run += v[k];
  }
}

__global__ void k_fill(const int* __restrict__ ei, const int* __restrict__ offsets,
                       int* __restrict__ cursor, int* __restrict__ csr_row) {
  int e = blockIdx.x * blockDim.x + threadIdx.x;
  if (e < N_EDGES) {
    int r = ei[e];
    int c = ei[N_EDGES + e];
    int p = atomicAdd(&cursor[c], 1);
    csr_row[offsets[c] + p] = r;
  }
}

// ------- xw' = (x @ W1) * dinv[row]  (fp32 vector GEMM, 32KB W k-chunks) -------
// 128-row block, 4 rows x 16 cols per thread. LDS 32KB -> 5 blocks/CU cap;
// __launch_bounds__(256,4) caps VGPR at 128 -> 4 waves/SIMD.
__global__ __launch_bounds__(256, 4) void k_gemm1(const float* __restrict__ x,
                                                  const float* __restrict__ W1,
                                                  const float* __restrict__ dinv,
                                                  float* __restrict__ xw) {
  __shared__ float Wl[64 * 128];  // 32 KB: 64 k-rows of W
  int t = threadIdx.x;
  int cg = t >> 5;  // 0..7 col group of 16 (2 distinct per wave -> bcast LDS reads)
  int rq = t & 31;  // row slot; rows interleaved stride 32
  int rbase = blockIdx.x * 128;
  float acc[4][16];
#pragma unroll
  for (int rr = 0; rr < 4; ++rr)
#pragma unroll
    for (int j = 0; j < 16; ++j) acc[rr][j] = 0.f;

  for (int kc = 0; kc < 128; kc += 64) {
    if (kc) __syncthreads();
    for (int i = t; i < 64 * 128 / 4; i += 256)
      ((float4*)Wl)[i] = ((const float4*)(W1 + (size_t)kc * 128))[i];
    __syncthreads();

    for (int k = 0; k < 64; k += 4) {
      float4 a[4];
#pragma unroll
      for (int rr = 0; rr < 4; ++rr) {
        int r = rbase + rq + 32 * rr;
        a[rr] = (r < N_NODES) ? *(const float4*)(x + (size_t)r * 128 + kc + k)
                              : make_float4(0.f, 0.f, 0.f, 0.f);
      }
#pragma unroll
      for (int kk = 0; kk < 4; ++kk) {
        const float4* wr = (const float4*)&Wl[(k + kk) * 128 + cg * 16];
        float4 w0 = wr[0], w1 = wr[1], w2 = wr[2], w3 = wr[3];
#pragma unroll
        for (int rr = 0; rr < 4; ++rr) {
          float av = (&a[rr].x)[kk];
          acc[rr][0] += av * w0.x;  acc[rr][1] += av * w0.y;
          acc[rr][2] += av * w0.z;  acc[rr][3] += av * w0.w;
          acc[rr][4] += av * w1.x;  acc[rr][5] += av * w1.y;
          acc[rr][6] += av * w1.z;  acc[rr][7] += av * w1.w;
          acc[rr][8] += av * w2.x;  acc[rr][9] += av * w2.y;
          acc[rr][10] += av * w2.z; acc[rr][11] += av * w2.w;
          acc[rr][12] += av * w3.x; acc[rr][13] += av * w3.y;
          acc[rr][14] += av * w3.z; acc[rr][15] += av * w3.w;
        }
      }
    }
  }

#pragma unroll
  for (int rr = 0; rr < 4; ++rr) {
    int r = rbase + rq + 32 * rr;
    if (r < N_NODES) {
      float d = dinv[r];
      float4* o = (float4*)(xw + (size_t)r * 128 + cg * 16);
#pragma unroll
      for (int q = 0; q < 4; ++q)
        o[q] = make_float4(acc[rr][q * 4] * d, acc[rr][q * 4 + 1] * d,
                           acc[rr][q * 4 + 2] * d, acc[rr][q * 4 + 3] * d);
    }
  }
}

// ----- conv1: per-node CSR gather of pre-scaled xw', h = relu(dc*Σ + b1) -----
__global__ __launch_bounds__(256) void k_conv1(const float* __restrict__ xw,
                                               const int* __restrict__ csr_row,
                                               const int* __restrict__ offsets,
                                               const int* __restrict__ deg,
                                               const float* __restrict__ dinv,
                                               const float* __restrict__ b1,
                                               float* __restrict__ h) {
  int lane = threadIdx.x & 63;
  int c = blockIdx.x * 4 + (threadIdx.x >> 6);  // one wave per node
  if (c >= N_NODES) return;
  float dc = dinv[c];
  const float2* base = (const float2*)xw;
  float2 self = base[(size_t)c * 64 + lane];  // = xw[c]*dinv[c]
  float acc0 = self.x;
  float acc1 = self.y;
  int st = offsets[c], cnt = deg[c];
  int s = 0;
  for (; s + 8 <= cnt; s += 8) {  // 8 independent gathers in flight
    int r0 = csr_row[st + s + 0];
    int r1 = csr_row[st + s + 1];
    int r2 = csr_row[st + s + 2];
    int r3 = csr_row[st + s + 3];
    int r4 = csr_row[st + s + 4];
    int r5 = csr_row[st + s + 5];
    int r6 = csr_row[st + s + 6];
    int r7 = csr_row[st + s + 7];
    float2 v0 = base[(size_t)r0 * 64 + lane];
    float2 v1 = base[(size_t)r1 * 64 + lane];
    float2 v2 = base[(size_t)r2 * 64 + lane];
    float2 v3 = base[(size_t)r3 * 64 + lane];
    float2 v4 = base[(size_t)r4 * 64 + lane];
    float2 v5 = base[(size_t)r5 * 64 + lane];
    float2 v6 = base[(size_t)r6 * 64 + lane];
    float2 v7 = base[(size_t)r7 * 64 + lane];
    acc0 += ((v0.x + v1.x) + (v2.x + v3.x)) + ((v4.x + v5.x) + (v6.x + v7.x));
    acc1 += ((v0.y + v1.y) + (v2.y + v3.y)) + ((v4.y + v5.y) + (v6.y + v7.y));
  }
  for (; s + 2 <= cnt; s += 2) {
    int r0 = csr_row[st + s + 0];
    int r1 = csr_row[st + s + 1];
    float2 v0 = base[(size_t)r0 * 64 + lane];
    float2 v1 = base[(size_t)r1 * 64 + lane];
    acc0 += v0.x + v1.x;
    acc1 += v0.y + v1.y;
  }
  for (; s < cnt; ++s) {
    int r = csr_row[st + s];
    float2 v = base[(size_t)r * 64 + lane];
    acc0 += v.x;
    acc1 += v.y;
  }
  float2 bb = ((const float2*)b1)[lane];
  float2 out;
  out.x = fmaxf(acc0 * dc + bb.x, 0.f);
  out.y = fmaxf(acc1 * dc + bb.y, 0.f);
  ((float2*)h)[(size_t)c * 64 + lane] = out;
}

// ----- coef[r][g] = Σ_{e from r, batch[col]=g} dinv[r]dinv[c]  (+self) -----
__global__ void k_coef_init(const int* __restrict__ batch, const float* __restrict__ dinv,
                            float* __restrict__ coef) {
  int i = blockIdx.x * blockDim.x + threadIdx.x;  // node*16+g
  if (i < N_NODES * N_GRAPHS) {
    int n = i >> 4, g = i & 15;
    float d = dinv[n];
    coef[i] = (g == batch[n]) ? d * d : 0.f;
  }
}

__global__ void k_coef_edge(const int* __restrict__ ei, const int* __restrict__ batch,
                            const float* __restrict__ dinv, float* __restrict__ coef) {
  int e = blockIdx.x * blockDim.x + threadIdx.x;
  if (e < N_EDGES) {
    int r = ei[e];
    int c = ei[N_EDGES + e];
    int g = batch[c];
    atomicAdd(&coef[r * N_GRAPHS + g], dinv[r] * dinv[c]);
  }
}

// ----- s[g][f] = Σ_r coef[r][g]*h[r][f]  (streaming; coef staged in LDS) -----
__global__ __launch_bounds__(256) void k_sum(const float* __restrict__ h,
                                             const float* __restrict__ coef,
                                             float* __restrict__ partials) {
  __shared__ float lds[8192];  // phase1: coef tile (16KB); phase2: wave partials (32KB)
  int t = threadIdx.x;
  int base = blockIdx.x * SUM_ROWS;

  for (int i = t; i < SUM_ROWS * 16 / 4; i += 256) {
    int gidx = base * 16 / 4 + i;
    float4 v = (gidx * 4 < N_NODES * 16) ? ((const float4*)coef)[gidx]
                                         : make_float4(0.f, 0.f, 0.f, 0.f);
    ((float4*)lds)[i] = v;
  }
  __syncthreads();

  int lane = t & 63;
  int q = t >> 6;  // wave id 0..3
  float2 acc[16];
#pragma unroll
  for (int g = 0; g < 16; ++g) acc[g] = make_float2(0.f, 0.f);

  const float2* h2 = (const float2*)h;
  for (int k = 0; k < SUM_ROWS / 4; ++k) {
    int lr = q + 4 * k;
    int r = base + lr;
    float2 hv = (r < N_NODES) ? h2[(size_t)r * 64 + lane] : make_float2(0.f, 0.f);
    const float4* cb = (const float4*)&lds[lr * 16];
    float4 c0 = cb[0], c1 = cb[1], c2 = cb[2], c3 = cb[3];
    acc[0].x += c0.x * hv.x;  acc[0].y += c0.x * hv.y;
    acc[1].x += c0.y * hv.x;  acc[1].y += c0.y * hv.y;
    acc[2].x += c0.z * hv.x;  acc[2].y += c0.z * hv.y;
    acc[3].x += c0.w * hv.x;  acc[3].y += c0.w * hv.y;
    acc[4].x += c1.x * hv.x;  acc[4].y += c1.x * hv.y;
    acc[5].x += c1.y * hv.x;  acc[5].y += c1.y * hv.y;
    acc[6].x += c1.z * hv.x;  acc[6].y += c1.z * hv.y;
    acc[7].x += c1.w * hv.x;  acc[7].y += c1.w * hv.y;
    acc[8].x += c2.x * hv.x;  acc[8].y += c2.x * hv.y;
    acc[9].x += c2.y * hv.x;  acc[9].y += c2.y * hv.y;
    acc[10].x += c2.z * hv.x; acc[10].y += c2.z * hv.y;
    acc[11].x += c2.w * hv.x; acc[11].y += c2.w * hv.y;
    acc[12].x += c3.x * hv.x; acc[12].y += c3.x * hv.y;
    acc[13].x += c3.y * hv.x; acc[13].y += c3.y * hv.y;
    acc[14].x += c3.z * hv.x; acc[14].y += c3.z * hv.y;
    acc[15].x += c3.w * hv.x; acc[15].y += c3.w * hv.y;
  }
  __syncthreads();
  float2* red = (float2*)lds;
#pragma unroll
  for (int g = 0; g < 16; ++g) red[(q * 16 + g) * 64 + lane] = acc[g];
  __syncthreads();
#pragma unroll
  for (int ii = 0; ii < 4; ++ii) {
    int i = t + ii * 256;
    int g = i >> 6, fp = i & 63;
    float2 sv = red[(0 * 16 + g) * 64 + fp];
    float2 s1 = red[(1 * 16 + g) * 64 + fp];
    float2 s2 = red[(2 * 16 + g) * 64 + fp];
    float2 s3 = red[(3 * 16 + g) * 64 + fp];
    sv.x += s1.x + s2.x + s3.x;
    sv.y += s1.y + s2.y + s3.y;
    ((float2*)partials)[(size_t)blockIdx.x * 1024 + g * 64 + fp] = sv;
  }
}

__global__ void k_reduce(const float* __restrict__ partials, float* __restrict__ sglob) {
  int i = blockIdx.x * blockDim.x + threadIdx.x;
  if (i < N_GRAPHS * 128) {
    float s = 0.f;
    for (int b = 0; b < SUM_NB; ++b) s += partials[(size_t)b * (N_GRAPHS * 128) + i];
    sglob[i] = s;
  }
}

// ---------------- final: counts, s@W2, mean, log_softmax ----------------
__global__ void k_final(const float* __restrict__ sglob, const int* __restrict__ batch,
                        const float* __restrict__ W2, const float* __restrict__ b2,
                        float* __restrict__ out) {
  __shared__ int bnd[N_GRAPHS + 1];
  int t = threadIdx.x;
  if (t <= N_GRAPHS) {
    if (t == N_GRAPHS) {
      bnd[t] = N_NODES;
    } else if (t == 0) {
      bnd[t] = 0;
    } else {
      int lo = 0, hi = N_NODES;
      while (lo < hi) {
        int mid = (lo + hi) >> 1;
        if (batch[mid] < t) lo = mid + 1; else hi = mid;
      }
      bnd[t] = lo;
    }
  }
  __syncthreads();
  if (t < N_GRAPHS) {
    float cnt = fmaxf((float)(bnd[t + 1] - bnd[t]), 1.0f);
    float p0 = 0.f, p1 = 0.f;
    const float* sg = sglob + t * 128;
    for (int f = 0; f < 128; ++f) {
      float sv = sg[f];
      p0 += sv * W2[f * 2 + 0];
      p1 += sv * W2[f * 2 + 1];
    }
    p0 = p0 / cnt + b2[0];
    p1 = p1 / cnt + b2[1];
    float m = fmaxf(p0, p1);
    float lse = m + logf(expf(p0 - m) + expf(p1 - m));
    out[t * 2 + 0] = p0 - lse;
    out[t * 2 + 1] = p1 - lse;
  }
}

// ---------------- launch ----------------
static inline size_t align256(size_t x) { return (x + 255) & ~(size_t)255; }

extern "C" void kernel_launch(void* const* d_in, const int* in_sizes, int n_in,
                              void* d_out, int out_size, void* d_ws, size_t ws_size,
                              hipStream_t stream) {
  (void)in_sizes; (void)n_in; (void)out_size; (void)ws_size;
  const float* x  = (const float*)d_in[0];
  const int*   ei = (const int*)d_in[1];   // [2][E]
  const int*   batch = (const int*)d_in[2];
  const float* W1 = (const float*)d_in[3];
  const float* b1 = (const float*)d_in[4];
  const float* W2 = (const float*)d_in[5];
  const float* b2 = (const float*)d_in[6];
  float* out = (float*)d_out;

  char* w = (char*)d_ws;
  size_t off = 0;
  float* xw = (float*)(w + off);       off = align256(off + (size_t)N_NODES * NHID * 4);
  float* coef = xw;                    // alias: coef written after conv1 (xw dead)
  float* h  = (float*)(w + off);       off = align256(off + (size_t)N_NODES * NHID * 4);
  int* csr_row = (int*)(w + off);      // alias with partials (partials used after conv1)
  float* partials = (float*)(w + off);
  size_t shared_sz = (size_t)SUM_NB * N_GRAPHS * 128 * 4;
  if ((size_t)N_EDGES * 4 > shared_sz) shared_sz = (size_t)N_EDGES * 4;
  off = align256(off + shared_sz);
  float* sglob = (float*)(w + off);    off = align256(off + (size_t)N_GRAPHS * 128 * 4);
  float* dinv = (float*)(w + off);     off = align256(off + (size_t)N_NODES * 4);
  int* deg = (int*)(w + off);          off = align256(off + (size_t)N_NODES * 4);
  int* cursor = (int*)(w + off);       off = align256(off + (size_t)N_NODES * 4);
  int* offsets = (int*)(w + off);      off = align256(off + (size_t)N_NODES * 4);
  int* csum = (int*)(w + off);         off = align256(off + (size_t)NCHUNK * 4);
  int* coff = (int*)(w + off);         off = align256(off + (size_t)NCHUNK * 4);

  k_zero2<<<(N_NODES + 255) / 256, 256, 0, stream>>>(deg, cursor);
  k_deg<<<(N_EDGES + 255) / 256, 256, 0, stream>>>(ei, deg);
  k_scan1<<<NCHUNK, 256, 0, stream>>>(deg, csum, dinv);
  k_scan2<<<1, 64, 0, stream>>>(csum, coff);
  k_scan3<<<NCHUNK, 256, 0, stream>>>(deg, coff, offsets);
  k_fill<<<(N_EDGES + 255) / 256, 256, 0, stream>>>(ei, offsets, cursor, csr_row);
  k_gemm1<<<(N_NODES + 127) / 128, 256, 0, stream>>>(x, W1, dinv, xw);
  k_conv1<<<(N_NODES + 3) / 4, 256, 0, stream>>>(xw, csr_row, offsets, deg, dinv, b1, h);
  // xw dead from here; coef aliases it
  k_coef_init<<<(N_NODES * N_GRAPHS + 255) / 256, 256, 0, stream>>>(batch, dinv, coef);
  k_coef_edge<<<(N_EDGES + 255) / 256, 256, 0, stream>>>(ei, batch, dinv, coef);
  k_sum<<<SUM_NB, 256, 0, stream>>>(h, coef, partials);
  k_reduce<<<8, 256, 0, stream>>>(partials, sglob);
  k_final<<<1, 64, 0, stream>>>(sglob, batch, W2, b2, out);
}

// Round 4
// 388.327 us; speedup vs baseline: 2.4715x; 1.1099x over previous
//
#include <hip/hip_runtime.h>
#include <hip/hip_bf16.h>

#define N_NODES 100000
#define N_EDGES 800000
#define N_GRAPHS 16
#define NFEAT 128
#define NHID 128
#define NCLASS 2

#define SCAN_CHUNK 2048
#define NCHUNK ((N_NODES + SCAN_CHUNK - 1) / SCAN_CHUNK)  // 49

#define SUM_ROWS 256
#define SUM_NB ((N_NODES + SUM_ROWS - 1) / SUM_ROWS)  // 391

// ---------------- utility ----------------
__global__ void k_zero2(int* __restrict__ a, int* __restrict__ b) {
  int i = blockIdx.x * blockDim.x + threadIdx.x;
  if (i < N_NODES) { a[i] = 0; b[i] = 0; }
}

// in-degree from edge targets (self-loop handled as +1 in dinv)
__global__ void k_deg(const int* __restrict__ ei, int* __restrict__ deg) {
  int e = blockIdx.x * blockDim.x + threadIdx.x;
  if (e < N_EDGES) atomicAdd(&deg[ei[N_EDGES + e]], 1);
}

// ---------------- exclusive scan of deg -> offsets (+ dinv fused) ----------------
__global__ void k_scan1(const int* __restrict__ deg, int* __restrict__ csum,
                        float* __restrict__ dinv) {
  __shared__ int lds[256];
  int b = blockIdx.x, t = threadIdx.x;
  int base = b * SCAN_CHUNK + t * 8;
  int s = 0;
#pragma unroll
  for (int k = 0; k < 8; ++k) {
    int i = base + k;
    int d = (i < N_NODES) ? deg[i] : 0;
    if (i < N_NODES) dinv[i] = rsqrtf((float)d + 1.0f);
    s += d;
  }
  lds[t] = s;
  __syncthreads();
  for (int off = 128; off > 0; off >>= 1) {
    if (t < off) lds[t] += lds[t + off];
    __syncthreads();
  }
  if (t == 0) csum[b] = lds[0];
}

__global__ void k_scan2(const int* __restrict__ csum, int* __restrict__ coff) {
  if (threadIdx.x == 0) {
    int run = 0;
    for (int i = 0; i < NCHUNK; ++i) { coff[i] = run; run += csum[i]; }
  }
}

__global__ void k_scan3(const int* __restrict__ deg, const int* __restrict__ coff,
                        int* __restrict__ offsets) {
  __shared__ int lds[256];
  int b = blockIdx.x, t = threadIdx.x;
  int base = b * SCAN_CHUNK + t * 8;
  int v[8];
  int s = 0;
#pragma unroll
  for (int k = 0; k < 8; ++k) {
    int i = base + k;
    v[k] = (i < N_NODES) ? deg[i] : 0;
    s += v[k];
  }
  lds[t] = s;
  __syncthreads();
  int total = s;
  for (int off = 1; off < 256; off <<= 1) {
    int x = (t >= off) ? lds[t - off] : 0;
    __syncthreads();
    lds[t] += x;
    __syncthreads();
  }
  int run = lds[t] - total + coff[b];
#pragma unroll
  for (int k = 0; k < 8; ++k) {
    int i = base + k;
    if (i < N_NODES) offsets[i] = run;
    run += v[k];
  }
}

__global__ void k_fill(const int* __restrict__ ei, const int* __restrict__ offsets,
                       int* __restrict__ cursor, int* __restrict__ csr_row) {
  int e = blockIdx.x * blockDim.x + threadIdx.x;
  if (e < N_EDGES) {
    int r = ei[e];
    int c = ei[N_EDGES + e];
    int p = atomicAdd(&cursor[c], 1);
    csr_row[offsets[c] + p] = r;
  }
}

// ------- xw' = (x @ W1) * dinv[row]  (fp32 GEMM, LDS-staged A and W) -------
// 128 rows x 128 cols per block, k-chunks of 32. A staged via LDS so global x
// reads are dense float4 streams (the R3 version's per-lane 512B-strided reads
// were the latency bottleneck: 64 cachelines per load instr, L1-thrashing).
// Al pad 33 -> compute reads hit bank (rq+k)%32, conflict-free.
__global__ __launch_bounds__(256, 4) void k_gemm1(const float* __restrict__ x,
                                                  const float* __restrict__ W1,
                                                  const float* __restrict__ dinv,
                                                  float* __restrict__ xw) {
  __shared__ float Al[128 * 33];  // 16.9 KB
  __shared__ float Wl[32 * 128];  // 16 KB
  int t = threadIdx.x;
  int cg = t >> 5;  // 0..7 col group of 16
  int rq = t & 31;  // row slot; rows rq, rq+32, rq+64, rq+96
  int rbase = blockIdx.x * 128;
  float acc[4][16];
#pragma unroll
  for (int rr = 0; rr < 4; ++rr)
#pragma unroll
    for (int j = 0; j < 16; ++j) acc[rr][j] = 0.f;

  for (int kc = 0; kc < 128; kc += 32) {
    if (kc) __syncthreads();
    // stage A tile: rows rbase..rbase+127, cols kc..kc+31 (coalesced float4)
#pragma unroll
    for (int i = 0; i < 4; ++i) {
      int f = t + i * 256;        // 0..1023
      int row = f >> 3, c4 = f & 7;
      int r = rbase + row;
      float4 v = (r < N_NODES) ? *(const float4*)(x + (size_t)r * 128 + kc + c4 * 4)
                               : make_float4(0.f, 0.f, 0.f, 0.f);
      float* dst = &Al[row * 33 + c4 * 4];
      dst[0] = v.x; dst[1] = v.y; dst[2] = v.z; dst[3] = v.w;
    }
    // stage W chunk: k-rows kc..kc+31 (coalesced float4)
#pragma unroll
    for (int i = 0; i < 4; ++i) {
      int f = t + i * 256;
      ((float4*)Wl)[f] = ((const float4*)(W1 + (size_t)kc * 128))[f];
    }
    __syncthreads();

#pragma unroll 4
    for (int k = 0; k < 32; ++k) {
      float a0 = Al[(rq + 0) * 33 + k];
      float a1 = Al[(rq + 32) * 33 + k];
      float a2 = Al[(rq + 64) * 33 + k];
      float a3 = Al[(rq + 96) * 33 + k];
      const float4* wr = (const float4*)&Wl[k * 128 + cg * 16];
      float4 w0 = wr[0], w1 = wr[1], w2 = wr[2], w3 = wr[3];
#define GCN_FMA(rr, av)                                              \
      acc[rr][0] += av * w0.x;  acc[rr][1] += av * w0.y;             \
      acc[rr][2] += av * w0.z;  acc[rr][3] += av * w0.w;             \
      acc[rr][4] += av * w1.x;  acc[rr][5] += av * w1.y;             \
      acc[rr][6] += av * w1.z;  acc[rr][7] += av * w1.w;             \
      acc[rr][8] += av * w2.x;  acc[rr][9] += av * w2.y;             \
      acc[rr][10] += av * w2.z; acc[rr][11] += av * w2.w;            \
      acc[rr][12] += av * w3.x; acc[rr][13] += av * w3.y;            \
      acc[rr][14] += av * w3.z; acc[rr][15] += av * w3.w;
      GCN_FMA(0, a0)
      GCN_FMA(1, a1)
      GCN_FMA(2, a2)
      GCN_FMA(3, a3)
#undef GCN_FMA
    }
  }

#pragma unroll
  for (int rr = 0; rr < 4; ++rr) {
    int r = rbase + rq + 32 * rr;
    if (r < N_NODES) {
      float d = dinv[r];
      float4* o = (float4*)(xw + (size_t)r * 128 + cg * 16);
#pragma unroll
      for (int q = 0; q < 4; ++q)
        o[q] = make_float4(acc[rr][q * 4] * d, acc[rr][q * 4 + 1] * d,
                           acc[rr][q * 4 + 2] * d, acc[rr][q * 4 + 3] * d);
    }
  }
}

// ----- conv1: per-node CSR gather of pre-scaled xw', h = relu(dc*Σ + b1) -----
__global__ __launch_bounds__(256) void k_conv1(const float* __restrict__ xw,
                                               const int* __restrict__ csr_row,
                                               const int* __restrict__ offsets,
                                               const int* __restrict__ deg,
                                               const float* __restrict__ dinv,
                                               const float* __restrict__ b1,
                                               float* __restrict__ h) {
  int lane = threadIdx.x & 63;
  int c = blockIdx.x * 4 + (threadIdx.x >> 6);  // one wave per node
  if (c >= N_NODES) return;
  float dc = dinv[c];
  const float2* base = (const float2*)xw;
  float2 self = base[(size_t)c * 64 + lane];  // = xw[c]*dinv[c]
  float acc0 = self.x;
  float acc1 = self.y;
  int st = offsets[c], cnt = deg[c];
  int s = 0;
  for (; s + 8 <= cnt; s += 8) {  // 8 independent gathers in flight
    int r0 = csr_row[st + s + 0];
    int r1 = csr_row[st + s + 1];
    int r2 = csr_row[st + s + 2];
    int r3 = csr_row[st + s + 3];
    int r4 = csr_row[st + s + 4];
    int r5 = csr_row[st + s + 5];
    int r6 = csr_row[st + s + 6];
    int r7 = csr_row[st + s + 7];
    float2 v0 = base[(size_t)r0 * 64 + lane];
    float2 v1 = base[(size_t)r1 * 64 + lane];
    float2 v2 = base[(size_t)r2 * 64 + lane];
    float2 v3 = base[(size_t)r3 * 64 + lane];
    float2 v4 = base[(size_t)r4 * 64 + lane];
    float2 v5 = base[(size_t)r5 * 64 + lane];
    float2 v6 = base[(size_t)r6 * 64 + lane];
    float2 v7 = base[(size_t)r7 * 64 + lane];
    acc0 += ((v0.x + v1.x) + (v2.x + v3.x)) + ((v4.x + v5.x) + (v6.x + v7.x));
    acc1 += ((v0.y + v1.y) + (v2.y + v3.y)) + ((v4.y + v5.y) + (v6.y + v7.y));
  }
  for (; s + 2 <= cnt; s += 2) {
    int r0 = csr_row[st + s + 0];
    int r1 = csr_row[st + s + 1];
    float2 v0 = base[(size_t)r0 * 64 + lane];
    float2 v1 = base[(size_t)r1 * 64 + lane];
    acc0 += v0.x + v1.x;
    acc1 += v0.y + v1.y;
  }
  for (; s < cnt; ++s) {
    int r = csr_row[st + s];
    float2 v = base[(size_t)r * 64 + lane];
    acc0 += v.x;
    acc1 += v.y;
  }
  float2 bb = ((const float2*)b1)[lane];
  float2 out;
  out.x = fmaxf(acc0 * dc + bb.x, 0.f);
  out.y = fmaxf(acc1 * dc + bb.y, 0.f);
  ((float2*)h)[(size_t)c * 64 + lane] = out;
}

// ----- coef[r][g] = Σ_{e from r, batch[col]=g} dinv[r]dinv[c]  (+self) -----
__global__ void k_coef_init(const int* __restrict__ batch, const float* __restrict__ dinv,
                            float* __restrict__ coef) {
  int i = blockIdx.x * blockDim.x + threadIdx.x;  // node*16+g
  if (i < N_NODES * N_GRAPHS) {
    int n = i >> 4, g = i & 15;
    float d = dinv[n];
    coef[i] = (g == batch[n]) ? d * d : 0.f;
  }
}

__global__ void k_coef_edge(const int* __restrict__ ei, const int* __restrict__ batch,
                            const float* __restrict__ dinv, float* __restrict__ coef) {
  int e = blockIdx.x * blockDim.x + threadIdx.x;
  if (e < N_EDGES) {
    int r = ei[e];
    int c = ei[N_EDGES + e];
    int g = batch[c];
    atomicAdd(&coef[r * N_GRAPHS + g], dinv[r] * dinv[c]);
  }
}

// ----- s[g][f] = Σ_r coef[r][g]*h[r][f]  (streaming; coef staged in LDS) -----
__global__ __launch_bounds__(256) void k_sum(const float* __restrict__ h,
                                             const float* __restrict__ coef,
                                             float* __restrict__ partials) {
  __shared__ float lds[8192];  // phase1: coef tile (16KB); phase2: wave partials (32KB)
  int t = threadIdx.x;
  int base = blockIdx.x * SUM_ROWS;

  for (int i = t; i < SUM_ROWS * 16 / 4; i += 256) {
    int gidx = base * 16 / 4 + i;
    float4 v = (gidx * 4 < N_NODES * 16) ? ((const float4*)coef)[gidx]
                                         : make_float4(0.f, 0.f, 0.f, 0.f);
    ((float4*)lds)[i] = v;
  }
  __syncthreads();

  int lane = t & 63;
  int q = t >> 6;  // wave id 0..3
  float2 acc[16];
#pragma unroll
  for (int g = 0; g < 16; ++g) acc[g] = make_float2(0.f, 0.f);

  const float2* h2 = (const float2*)h;
  for (int k = 0; k < SUM_ROWS / 4; ++k) {
    int lr = q + 4 * k;
    int r = base + lr;
    float2 hv = (r < N_NODES) ? h2[(size_t)r * 64 + lane] : make_float2(0.f, 0.f);
    const float4* cb = (const float4*)&lds[lr * 16];
    float4 c0 = cb[0], c1 = cb[1], c2 = cb[2], c3 = cb[3];
    acc[0].x += c0.x * hv.x;  acc[0].y += c0.x * hv.y;
    acc[1].x += c0.y * hv.x;  acc[1].y += c0.y * hv.y;
    acc[2].x += c0.z * hv.x;  acc[2].y += c0.z * hv.y;
    acc[3].x += c0.w * hv.x;  acc[3].y += c0.w * hv.y;
    acc[4].x += c1.x * hv.x;  acc[4].y += c1.x * hv.y;
    acc[5].x += c1.y * hv.x;  acc[5].y += c1.y * hv.y;
    acc[6].x += c1.z * hv.x;  acc[6].y += c1.z * hv.y;
    acc[7].x += c1.w * hv.x;  acc[7].y += c1.w * hv.y;
    acc[8].x += c2.x * hv.x;  acc[8].y += c2.x * hv.y;
    acc[9].x += c2.y * hv.x;  acc[9].y += c2.y * hv.y;
    acc[10].x += c2.z * hv.x; acc[10].y += c2.z * hv.y;
    acc[11].x += c2.w * hv.x; acc[11].y += c2.w * hv.y;
    acc[12].x += c3.x * hv.x; acc[12].y += c3.x * hv.y;
    acc[13].x += c3.y * hv.x; acc[13].y += c3.y * hv.y;
    acc[14].x += c3.z * hv.x; acc[14].y += c3.z * hv.y;
    acc[15].x += c3.w * hv.x; acc[15].y += c3.w * hv.y;
  }
  __syncthreads();
  float2* red = (float2*)lds;
#pragma unroll
  for (int g = 0; g < 16; ++g) red[(q * 16 + g) * 64 + lane] = acc[g];
  __syncthreads();
#pragma unroll
  for (int ii = 0; ii < 4; ++ii) {
    int i = t + ii * 256;
    int g = i >> 6, fp = i & 63;
    float2 sv = red[(0 * 16 + g) * 64 + fp];
    float2 s1 = red[(1 * 16 + g) * 64 + fp];
    float2 s2 = red[(2 * 16 + g) * 64 + fp];
    float2 s3 = red[(3 * 16 + g) * 64 + fp];
    sv.x += s1.x + s2.x + s3.x;
    sv.y += s1.y + s2.y + s3.y;
    ((float2*)partials)[(size_t)blockIdx.x * 1024 + g * 64 + fp] = sv;
  }
}

__global__ void k_reduce(const float* __restrict__ partials, float* __restrict__ sglob) {
  int i = blockIdx.x * blockDim.x + threadIdx.x;
  if (i < N_GRAPHS * 128) {
    float s = 0.f;
    for (int b = 0; b < SUM_NB; ++b) s += partials[(size_t)b * (N_GRAPHS * 128) + i];
    sglob[i] = s;
  }
}

// ---------------- final: counts, s@W2, mean, log_softmax ----------------
__global__ void k_final(const float* __restrict__ sglob, const int* __restrict__ batch,
                        const float* __restrict__ W2, const float* __restrict__ b2,
                        float* __restrict__ out) {
  __shared__ int bnd[N_GRAPHS + 1];
  int t = threadIdx.x;
  if (t <= N_GRAPHS) {
    if (t == N_GRAPHS) {
      bnd[t] = N_NODES;
    } else if (t == 0) {
      bnd[t] = 0;
    } else {
      int lo = 0, hi = N_NODES;
      while (lo < hi) {
        int mid = (lo + hi) >> 1;
        if (batch[mid] < t) lo = mid + 1; else hi = mid;
      }
      bnd[t] = lo;
    }
  }
  __syncthreads();
  if (t < N_GRAPHS) {
    float cnt = fmaxf((float)(bnd[t + 1] - bnd[t]), 1.0f);
    float p0 = 0.f, p1 = 0.f;
    const float* sg = sglob + t * 128;
    for (int f = 0; f < 128; ++f) {
      float sv = sg[f];
      p0 += sv * W2[f * 2 + 0];
      p1 += sv * W2[f * 2 + 1];
    }
    p0 = p0 / cnt + b2[0];
    p1 = p1 / cnt + b2[1];
    float m = fmaxf(p0, p1);
    float lse = m + logf(expf(p0 - m) + expf(p1 - m));
    out[t * 2 + 0] = p0 - lse;
    out[t * 2 + 1] = p1 - lse;
  }
}

// ---------------- launch ----------------
static inline size_t align256(size_t x) { return (x + 255) & ~(size_t)255; }

extern "C" void kernel_launch(void* const* d_in, const int* in_sizes, int n_in,
                              void* d_out, int out_size, void* d_ws, size_t ws_size,
                              hipStream_t stream) {
  (void)in_sizes; (void)n_in; (void)out_size; (void)ws_size;
  const float* x  = (const float*)d_in[0];
  const int*   ei = (const int*)d_in[1];   // [2][E]
  const int*   batch = (const int*)d_in[2];
  const float* W1 = (const float*)d_in[3];
  const float* b1 = (const float*)d_in[4];
  const float* W2 = (const float*)d_in[5];
  const float* b2 = (const float*)d_in[6];
  float* out = (float*)d_out;

  char* w = (char*)d_ws;
  size_t off = 0;
  float* xw = (float*)(w + off);       off = align256(off + (size_t)N_NODES * NHID * 4);
  float* coef = xw;                    // alias: coef written after conv1 (xw dead)
  float* h  = (float*)(w + off);       off = align256(off + (size_t)N_NODES * NHID * 4);
  int* csr_row = (int*)(w + off);      // alias with partials (partials used after conv1)
  float* partials = (float*)(w + off);
  size_t shared_sz = (size_t)SUM_NB * N_GRAPHS * 128 * 4;
  if ((size_t)N_EDGES * 4 > shared_sz) shared_sz = (size_t)N_EDGES * 4;
  off = align256(off + shared_sz);
  float* sglob = (float*)(w + off);    off = align256(off + (size_t)N_GRAPHS * 128 * 4);
  float* dinv = (float*)(w + off);     off = align256(off + (size_t)N_NODES * 4);
  int* deg = (int*)(w + off);          off = align256(off + (size_t)N_NODES * 4);
  int* cursor = (int*)(w + off);       off = align256(off + (size_t)N_NODES * 4);
  int* offsets = (int*)(w + off);      off = align256(off + (size_t)N_NODES * 4);
  int* csum = (int*)(w + off);         off = align256(off + (size_t)NCHUNK * 4);
  int* coff = (int*)(w + off);         off = align256(off + (size_t)NCHUNK * 4);

  k_zero2<<<(N_NODES + 255) / 256, 256, 0, stream>>>(deg, cursor);
  k_deg<<<(N_EDGES + 255) / 256, 256, 0, stream>>>(ei, deg);
  k_scan1<<<NCHUNK, 256, 0, stream>>>(deg, csum, dinv);
  k_scan2<<<1, 64, 0, stream>>>(csum, coff);
  k_scan3<<<NCHUNK, 256, 0, stream>>>(deg, coff, offsets);
  k_fill<<<(N_EDGES + 255) / 256, 256, 0, stream>>>(ei, offsets, cursor, csr_row);
  k_gemm1<<<(N_NODES + 127) / 128, 256, 0, stream>>>(x, W1, dinv, xw);
  k_conv1<<<(N_NODES + 3) / 4, 256, 0, stream>>>(xw, csr_row, offsets, deg, dinv, b1, h);
  // xw dead from here; coef aliases it
  k_coef_init<<<(N_NODES * N_GRAPHS + 255) / 256, 256, 0, stream>>>(batch, dinv, coef);
  k_coef_edge<<<(N_EDGES + 255) / 256, 256, 0, stream>>>(ei, batch, dinv, coef);
  k_sum<<<SUM_NB, 256, 0, stream>>>(h, coef, partials);
  k_reduce<<<8, 256, 0, stream>>>(partials, sglob);
  k_final<<<1, 64, 0, stream>>>(sglob, batch, W2, b2, out);
}

// Round 5
// 365.910 us; speedup vs baseline: 2.6230x; 1.0613x over previous
//
#include <hip/hip_runtime.h>
#include <hip/hip_bf16.h>

#define N_NODES 100000
#define N_EDGES 800000
#define N_GRAPHS 16
#define NFEAT 128
#define NHID 128
#define NCLASS 2

#define SCAN_CHUNK 2048
#define NCHUNK ((N_NODES + SCAN_CHUNK - 1) / SCAN_CHUNK)  // 49

#define SUM_ROWS 256
#define SUM_NB ((N_NODES + SUM_ROWS - 1) / SUM_ROWS)  // 391

typedef unsigned int uint32;
typedef unsigned short ushort16;

// ---- bf16 helpers (manual RNE; low ushort = first element of the pair) ----
__device__ __forceinline__ unsigned short f2bf(float f) {
  unsigned u = __float_as_uint(f);
  unsigned r = (u + 0x7fffu + ((u >> 16) & 1u)) >> 16;
  return (unsigned short)r;
}
__device__ __forceinline__ uint32 bfpack(float a, float b) {
  return (uint32)f2bf(a) | ((uint32)f2bf(b) << 16);
}
__device__ __forceinline__ float bflo(uint32 u) { return __uint_as_float(u << 16); }
__device__ __forceinline__ float bfhi(uint32 u) { return __uint_as_float(u & 0xffff0000u); }

// ---------------- utility ----------------
__global__ void k_zero2(int* __restrict__ a, int* __restrict__ b) {
  int i = blockIdx.x * blockDim.x + threadIdx.x;
  if (i < N_NODES) { a[i] = 0; b[i] = 0; }
}

// in-degree from edge targets (self-loop handled as +1 in dinv)
__global__ void k_deg(const int* __restrict__ ei, int* __restrict__ deg) {
  int e = blockIdx.x * blockDim.x + threadIdx.x;
  if (e < N_EDGES) atomicAdd(&deg[ei[N_EDGES + e]], 1);
}

// ---------------- scan of deg -> offsets (+ dinv fused) ----------------
__global__ void k_scan1(const int* __restrict__ deg, int* __restrict__ csum,
                        float* __restrict__ dinv) {
  __shared__ int lds[256];
  int b = blockIdx.x, t = threadIdx.x;
  int base = b * SCAN_CHUNK + t * 8;
  int s = 0;
#pragma unroll
  for (int k = 0; k < 8; ++k) {
    int i = base + k;
    int d = (i < N_NODES) ? deg[i] : 0;
    if (i < N_NODES) dinv[i] = rsqrtf((float)d + 1.0f);
    s += d;
  }
  lds[t] = s;
  __syncthreads();
  for (int off = 128; off > 0; off >>= 1) {
    if (t < off) lds[t] += lds[t + off];
    __syncthreads();
  }
  if (t == 0) csum[b] = lds[0];
}

// scan3 now also derives its chunk offset from csum (scan2 merged in)
__global__ void k_scan3(const int* __restrict__ deg, const int* __restrict__ csum,
                        int* __restrict__ offsets) {
  __shared__ int lds[256];
  __shared__ int soff;
  int b = blockIdx.x, t = threadIdx.x;
  if (t == 0) {
    int run = 0;
    for (int i = 0; i < b; ++i) run += csum[i];
    soff = run;
  }
  int base = b * SCAN_CHUNK + t * 8;
  int v[8];
  int s = 0;
#pragma unroll
  for (int k = 0; k < 8; ++k) {
    int i = base + k;
    v[k] = (i < N_NODES) ? deg[i] : 0;
    s += v[k];
  }
  lds[t] = s;
  __syncthreads();
  int total = s;
  for (int off = 1; off < 256; off <<= 1) {
    int x = (t >= off) ? lds[t - off] : 0;
    __syncthreads();
    lds[t] += x;
    __syncthreads();
  }
  int run = lds[t] - total + soff;
#pragma unroll
  for (int k = 0; k < 8; ++k) {
    int i = base + k;
    if (i < N_NODES) offsets[i] = run;
    run += v[k];
  }
}

__global__ void k_fill(const int* __restrict__ ei, const int* __restrict__ offsets,
                       int* __restrict__ cursor, int* __restrict__ csr_row) {
  int e = blockIdx.x * blockDim.x + threadIdx.x;
  if (e < N_EDGES) {
    int r = ei[e];
    int c = ei[N_EDGES + e];
    int p = atomicAdd(&cursor[c], 1);
    csr_row[offsets[c] + p] = r;
  }
}

// ------- xw' = (x @ W1) * dinv[row], stored bf16 -------
// 256 rows x 128 cols per block; 8 rows x 16 cols per thread (LDS:VALU balanced:
// per wave per k ~72 LDS-pipe cyc vs 64 VALU-wall cyc; R4's 4x16 tile was 71:32
// LDS-bound). A read as b128 over 4 k; Al stride 36 keeps 16B align + 2-way banks.
__global__ __launch_bounds__(256, 2) void k_gemm1(const float* __restrict__ x,
                                                  const float* __restrict__ W1,
                                                  const float* __restrict__ dinv,
                                                  ushort16* __restrict__ xw) {
  __shared__ float Al[256 * 36];  // 36.9 KB
  __shared__ float Wl[32 * 128];  // 16 KB
  int t = threadIdx.x;
  int cg = t >> 5;  // 0..7 col group of 16
  int rq = t & 31;  // row slot; rows rq + 32*rr
  int rbase = blockIdx.x * 256;
  float acc[8][16];
#pragma unroll
  for (int rr = 0; rr < 8; ++rr)
#pragma unroll
    for (int j = 0; j < 16; ++j) acc[rr][j] = 0.f;

#pragma unroll 1
  for (int kc = 0; kc < 128; kc += 32) {
    if (kc) __syncthreads();
    // stage A tile: 256 rows x 32 cols, coalesced float4
#pragma unroll
    for (int i = 0; i < 8; ++i) {
      int f = t + i * 256;  // 0..2047
      int row = f >> 3, c4 = f & 7;
      int r = rbase + row;
      float4 v = (r < N_NODES) ? *(const float4*)(x + (size_t)r * 128 + kc + c4 * 4)
                               : make_float4(0.f, 0.f, 0.f, 0.f);
      *(float4*)&Al[row * 36 + c4 * 4] = v;
    }
    // stage W chunk: 32 k-rows
#pragma unroll
    for (int i = 0; i < 4; ++i) {
      int f = t + i * 256;
      ((float4*)Wl)[f] = ((const float4*)(W1 + (size_t)kc * 128))[f];
    }
    __syncthreads();

#pragma unroll 1
    for (int k4 = 0; k4 < 8; ++k4) {
      float4 a[8];
#pragma unroll
      for (int rr = 0; rr < 8; ++rr)
        a[rr] = *(const float4*)&Al[(rq + 32 * rr) * 36 + k4 * 4];
#pragma unroll
      for (int kk = 0; kk < 4; ++kk) {
        const float4* wr = (const float4*)&Wl[(k4 * 4 + kk) * 128 + cg * 16];
        float4 w0 = wr[0], w1 = wr[1], w2 = wr[2], w3 = wr[3];
#pragma unroll
        for (int rr = 0; rr < 8; ++rr) {
          float av = (&a[rr].x)[kk];
          acc[rr][0] += av * w0.x;  acc[rr][1] += av * w0.y;
          acc[rr][2] += av * w0.z;  acc[rr][3] += av * w0.w;
          acc[rr][4] += av * w1.x;  acc[rr][5] += av * w1.y;
          acc[rr][6] += av * w1.z;  acc[rr][7] += av * w1.w;
          acc[rr][8] += av * w2.x;  acc[rr][9] += av * w2.y;
          acc[rr][10] += av * w2.z; acc[rr][11] += av * w2.w;
          acc[rr][12] += av * w3.x; acc[rr][13] += av * w3.y;
          acc[rr][14] += av * w3.z; acc[rr][15] += av * w3.w;
        }
      }
    }
  }

#pragma unroll
  for (int rr = 0; rr < 8; ++rr) {
    int r = rbase + rq + 32 * rr;
    if (r < N_NODES) {
      float d = dinv[r];
      uint32 o[8];
#pragma unroll
      for (int j = 0; j < 8; ++j)
        o[j] = bfpack(acc[rr][2 * j] * d, acc[rr][2 * j + 1] * d);
      uint32* dst = (uint32*)(xw + (size_t)r * 128 + cg * 16);
      *(uint4*)(dst + 0) = make_uint4(o[0], o[1], o[2], o[3]);
      *(uint4*)(dst + 4) = make_uint4(o[4], o[5], o[6], o[7]);
    }
  }
}

// ----- conv1: per-node CSR gather of bf16 xw', h = relu(dc*Σ + b1), bf16 out -----
__global__ __launch_bounds__(256) void k_conv1(const ushort16* __restrict__ xw,
                                               const int* __restrict__ csr_row,
                                               const int* __restrict__ offsets,
                                               const int* __restrict__ deg,
                                               const float* __restrict__ dinv,
                                               const float* __restrict__ b1,
                                               ushort16* __restrict__ h) {
  int lane = threadIdx.x & 63;
  int c = blockIdx.x * 4 + (threadIdx.x >> 6);  // one wave per node
  if (c >= N_NODES) return;
  float dc = dinv[c];
  const uint32* base = (const uint32*)xw;  // row = 64 uints (128 bf16)
  uint32 su = base[(size_t)c * 64 + lane];
  float acc0 = bflo(su);
  float acc1 = bfhi(su);
  int st = offsets[c], cnt = deg[c];
  int s = 0;
  for (; s + 8 <= cnt; s += 8) {  // 8 independent gathers in flight
    int r0 = csr_row[st + s + 0];
    int r1 = csr_row[st + s + 1];
    int r2 = csr_row[st + s + 2];
    int r3 = csr_row[st + s + 3];
    int r4 = csr_row[st + s + 4];
    int r5 = csr_row[st + s + 5];
    int r6 = csr_row[st + s + 6];
    int r7 = csr_row[st + s + 7];
    uint32 u0 = base[(size_t)r0 * 64 + lane];
    uint32 u1 = base[(size_t)r1 * 64 + lane];
    uint32 u2 = base[(size_t)r2 * 64 + lane];
    uint32 u3 = base[(size_t)r3 * 64 + lane];
    uint32 u4 = base[(size_t)r4 * 64 + lane];
    uint32 u5 = base[(size_t)r5 * 64 + lane];
    uint32 u6 = base[(size_t)r6 * 64 + lane];
    uint32 u7 = base[(size_t)r7 * 64 + lane];
    acc0 += ((bflo(u0) + bflo(u1)) + (bflo(u2) + bflo(u3))) +
            ((bflo(u4) + bflo(u5)) + (bflo(u6) + bflo(u7)));
    acc1 += ((bfhi(u0) + bfhi(u1)) + (bfhi(u2) + bfhi(u3))) +
            ((bfhi(u4) + bfhi(u5)) + (bfhi(u6) + bfhi(u7)));
  }
  for (; s + 2 <= cnt; s += 2) {
    int r0 = csr_row[st + s + 0];
    int r1 = csr_row[st + s + 1];
    uint32 u0 = base[(size_t)r0 * 64 + lane];
    uint32 u1 = base[(size_t)r1 * 64 + lane];
    acc0 += bflo(u0) + bflo(u1);
    acc1 += bfhi(u0) + bfhi(u1);
  }
  for (; s < cnt; ++s) {
    int r = csr_row[st + s];
    uint32 u = base[(size_t)r * 64 + lane];
    acc0 += bflo(u);
    acc1 += bfhi(u);
  }
  float2 bb = ((const float2*)b1)[lane];
  float o0 = fmaxf(acc0 * dc + bb.x, 0.f);
  float o1 = fmaxf(acc1 * dc + bb.y, 0.f);
  ((uint32*)h)[(size_t)c * 64 + lane] = bfpack(o0, o1);
}

// ----- coef[r][g] = Σ_{e from r, batch[col]=g} dinv[r]dinv[c]  (+self) -----
__global__ void k_coef_init(const int* __restrict__ batch, const float* __restrict__ dinv,
                            float* __restrict__ coef) {
  int i = blockIdx.x * blockDim.x + threadIdx.x;  // node*16+g
  if (i < N_NODES * N_GRAPHS) {
    int n = i >> 4, g = i & 15;
    float d = dinv[n];
    coef[i] = (g == batch[n]) ? d * d : 0.f;
  }
}

__global__ void k_coef_edge(const int* __restrict__ ei, const int* __restrict__ batch,
                            const float* __restrict__ dinv, float* __restrict__ coef) {
  int e = blockIdx.x * blockDim.x + threadIdx.x;
  if (e < N_EDGES) {
    int r = ei[e];
    int c = ei[N_EDGES + e];
    int g = batch[c];
    atomicAdd(&coef[r * N_GRAPHS + g], dinv[r] * dinv[c]);
  }
}

// ----- s[g][f] = Σ_r coef[r][g]*h[r][f]  (streaming bf16 h; coef in LDS) -----
__global__ __launch_bounds__(256) void k_sum(const ushort16* __restrict__ h,
                                             const float* __restrict__ coef,
                                             float* __restrict__ partials) {
  __shared__ float lds[8192];  // phase1: coef tile (16KB); phase2: wave partials (32KB)
  int t = threadIdx.x;
  int base = blockIdx.x * SUM_ROWS;

  for (int i = t; i < SUM_ROWS * 16 / 4; i += 256) {
    int gidx = base * 16 / 4 + i;
    float4 v = (gidx * 4 < N_NODES * 16) ? ((const float4*)coef)[gidx]
                                         : make_float4(0.f, 0.f, 0.f, 0.f);
    ((float4*)lds)[i] = v;
  }
  __syncthreads();

  int lane = t & 63;
  int q = t >> 6;  // wave id 0..3
  float2 acc[16];
#pragma unroll
  for (int g = 0; g < 16; ++g) acc[g] = make_float2(0.f, 0.f);

  const uint32* h2 = (const uint32*)h;
  for (int k = 0; k < SUM_ROWS / 4; ++k) {
    int lr = q + 4 * k;
    int r = base + lr;
    uint32 u = (r < N_NODES) ? h2[(size_t)r * 64 + lane] : 0u;
    float hx = bflo(u), hy = bfhi(u);
    const float4* cb = (const float4*)&lds[lr * 16];
    float4 c0 = cb[0], c1 = cb[1], c2 = cb[2], c3 = cb[3];
    acc[0].x += c0.x * hx;  acc[0].y += c0.x * hy;
    acc[1].x += c0.y * hx;  acc[1].y += c0.y * hy;
    acc[2].x += c0.z * hx;  acc[2].y += c0.z * hy;
    acc[3].x += c0.w * hx;  acc[3].y += c0.w * hy;
    acc[4].x += c1.x * hx;  acc[4].y += c1.x * hy;
    acc[5].x += c1.y * hx;  acc[5].y += c1.y * hy;
    acc[6].x += c1.z * hx;  acc[6].y += c1.z * hy;
    acc[7].x += c1.w * hx;  acc[7].y += c1.w * hy;
    acc[8].x += c2.x * hx;  acc[8].y += c2.x * hy;
    acc[9].x += c2.y * hx;  acc[9].y += c2.y * hy;
    acc[10].x += c2.z * hx; acc[10].y += c2.z * hy;
    acc[11].x += c2.w * hx; acc[11].y += c2.w * hy;
    acc[12].x += c3.x * hx; acc[12].y += c3.x * hy;
    acc[13].x += c3.y * hx; acc[13].y += c3.y * hy;
    acc[14].x += c3.z * hx; acc[14].y += c3.z * hy;
    acc[15].x += c3.w * hx; acc[15].y += c3.w * hy;
  }
  __syncthreads();
  float2* red = (float2*)lds;
#pragma unroll
  for (int g = 0; g < 16; ++g) red[(q * 16 + g) * 64 + lane] = acc[g];
  __syncthreads();
#pragma unroll
  for (int ii = 0; ii < 4; ++ii) {
    int i = t + ii * 256;
    int g = i >> 6, fp = i & 63;
    float2 sv = red[(0 * 16 + g) * 64 + fp];
    float2 s1 = red[(1 * 16 + g) * 64 + fp];
    float2 s2 = red[(2 * 16 + g) * 64 + fp];
    float2 s3 = red[(3 * 16 + g) * 64 + fp];
    sv.x += s1.x + s2.x + s3.x;
    sv.y += s1.y + s2.y + s3.y;
    ((float2*)partials)[(size_t)blockIdx.x * 1024 + g * 64 + fp] = sv;
  }
}

__global__ void k_reduce(const float* __restrict__ partials, float* __restrict__ sglob) {
  int i = blockIdx.x * blockDim.x + threadIdx.x;
  if (i < N_GRAPHS * 128) {
    float s = 0.f;
    for (int b = 0; b < SUM_NB; ++b) s += partials[(size_t)b * (N_GRAPHS * 128) + i];
    sglob[i] = s;
  }
}

// ---------------- final: counts, s@W2, mean, log_softmax ----------------
__global__ void k_final(const float* __restrict__ sglob, const int* __restrict__ batch,
                        const float* __restrict__ W2, const float* __restrict__ b2,
                        float* __restrict__ out) {
  __shared__ int bnd[N_GRAPHS + 1];
  int t = threadIdx.x;
  if (t <= N_GRAPHS) {
    if (t == N_GRAPHS) {
      bnd[t] = N_NODES;
    } else if (t == 0) {
      bnd[t] = 0;
    } else {
      int lo = 0, hi = N_NODES;
      while (lo < hi) {
        int mid = (lo + hi) >> 1;
        if (batch[mid] < t) lo = mid + 1; else hi = mid;
      }
      bnd[t] = lo;
    }
  }
  __syncthreads();
  if (t < N_GRAPHS) {
    float cnt = fmaxf((float)(bnd[t + 1] - bnd[t]), 1.0f);
    float p0 = 0.f, p1 = 0.f;
    const float* sg = sglob + t * 128;
    for (int f = 0; f < 128; ++f) {
      float sv = sg[f];
      p0 += sv * W2[f * 2 + 0];
      p1 += sv * W2[f * 2 + 1];
    }
    p0 = p0 / cnt + b2[0];
    p1 = p1 / cnt + b2[1];
    float m = fmaxf(p0, p1);
    float lse = m + logf(expf(p0 - m) + expf(p1 - m));
    out[t * 2 + 0] = p0 - lse;
    out[t * 2 + 1] = p1 - lse;
  }
}

// ---------------- launch ----------------
static inline size_t align256(size_t x) { return (x + 255) & ~(size_t)255; }

extern "C" void kernel_launch(void* const* d_in, const int* in_sizes, int n_in,
                              void* d_out, int out_size, void* d_ws, size_t ws_size,
                              hipStream_t stream) {
  (void)in_sizes; (void)n_in; (void)out_size; (void)ws_size;
  const float* x  = (const float*)d_in[0];
  const int*   ei = (const int*)d_in[1];   // [2][E]
  const int*   batch = (const int*)d_in[2];
  const float* W1 = (const float*)d_in[3];
  const float* b1 = (const float*)d_in[4];
  const float* W2 = (const float*)d_in[5];
  const float* b2 = (const float*)d_in[6];
  float* out = (float*)d_out;

  char* w = (char*)d_ws;
  size_t off = 0;
  ushort16* xw = (ushort16*)(w + off);  off = align256(off + (size_t)N_NODES * NHID * 2);
  ushort16* h  = (ushort16*)(w + off);  off = align256(off + (size_t)N_NODES * NHID * 2);
  float* coef = (float*)(w + off);      off = align256(off + (size_t)N_NODES * N_GRAPHS * 4);
  int* csr_row = (int*)(w + off);       // alias with partials (partials used after conv1)
  float* partials = (float*)(w + off);
  size_t shared_sz = (size_t)SUM_NB * N_GRAPHS * 128 * 4;
  if ((size_t)N_EDGES * 4 > shared_sz) shared_sz = (size_t)N_EDGES * 4;
  off = align256(off + shared_sz);
  float* sglob = (float*)(w + off);     off = align256(off + (size_t)N_GRAPHS * 128 * 4);
  float* dinv = (float*)(w + off);      off = align256(off + (size_t)N_NODES * 4);
  int* deg = (int*)(w + off);           off = align256(off + (size_t)N_NODES * 4);
  int* cursor = (int*)(w + off);        off = align256(off + (size_t)N_NODES * 4);
  int* offsets = (int*)(w + off);       off = align256(off + (size_t)N_NODES * 4);
  int* csum = (int*)(w + off);          off = align256(off + (size_t)NCHUNK * 4);

  k_zero2<<<(N_NODES + 255) / 256, 256, 0, stream>>>(deg, cursor);
  k_deg<<<(N_EDGES + 255) / 256, 256, 0, stream>>>(ei, deg);
  k_scan1<<<NCHUNK, 256, 0, stream>>>(deg, csum, dinv);
  k_scan3<<<NCHUNK, 256, 0, stream>>>(deg, csum, offsets);
  k_fill<<<(N_EDGES + 255) / 256, 256, 0, stream>>>(ei, offsets, cursor, csr_row);
  k_gemm1<<<(N_NODES + 255) / 256, 256, 0, stream>>>(x, W1, dinv, xw);
  k_conv1<<<(N_NODES + 3) / 4, 256, 0, stream>>>(xw, csr_row, offsets, deg, dinv, b1, h);
  k_coef_init<<<(N_NODES * N_GRAPHS + 255) / 256, 256, 0, stream>>>(batch, dinv, coef);
  k_coef_edge<<<(N_EDGES + 255) / 256, 256, 0, stream>>>(ei, batch, dinv, coef);
  k_sum<<<SUM_NB, 256, 0, stream>>>(h, coef, partials);
  k_reduce<<<8, 256, 0, stream>>>(partials, sglob);
  k_final<<<1, 64, 0, stream>>>(sglob, batch, W2, b2, out);
}

// Round 6
// 327.814 us; speedup vs baseline: 2.9278x; 1.1162x over previous
//
#include <hip/hip_runtime.h>
#include <hip/hip_bf16.h>

#define N_NODES 100000
#define N_EDGES 800000
#define N_GRAPHS 16
#define NFEAT 128
#define NHID 128
#define NCLASS 2

#define SCAN_CHUNK 2048
#define NCHUNK ((N_NODES + SCAN_CHUNK - 1) / SCAN_CHUNK)  // 49

#define SUM_ROWS 256
#define SUM_NB ((N_NODES + SUM_ROWS - 1) / SUM_ROWS)  // 391

#define GEMM_BLOCKS 512
#define N_CHUNKS (N_NODES / 16)  // 6250 exact

typedef unsigned int uint32;
typedef unsigned short ushort16;
typedef __attribute__((ext_vector_type(8))) short short8;
typedef __attribute__((ext_vector_type(4))) float f32x4;

// ---- bf16 helpers (manual RNE; low ushort = first element of the pair) ----
__device__ __forceinline__ unsigned short f2bf(float f) {
  unsigned u = __float_as_uint(f);
  unsigned r = (u + 0x7fffu + ((u >> 16) & 1u)) >> 16;
  return (unsigned short)r;
}
__device__ __forceinline__ uint32 bfpack(float a, float b) {
  return (uint32)f2bf(a) | ((uint32)f2bf(b) << 16);
}
__device__ __forceinline__ float bflo(uint32 u) { return __uint_as_float(u << 16); }
__device__ __forceinline__ float bfhi(uint32 u) { return __uint_as_float(u & 0xffff0000u); }

// ---------------- utility ----------------
__global__ void k_zero2(int* __restrict__ a, int* __restrict__ b) {
  int i = blockIdx.x * blockDim.x + threadIdx.x;
  if (i < N_NODES) { a[i] = 0; b[i] = 0; }
}

// in-degree from edge targets (self-loop handled as +1 in dinv)
__global__ void k_deg(const int* __restrict__ ei, int* __restrict__ deg) {
  int e = blockIdx.x * blockDim.x + threadIdx.x;
  if (e < N_EDGES) atomicAdd(&deg[ei[N_EDGES + e]], 1);
}

// ---------------- scan of deg -> offsets (+ dinv fused) ----------------
__global__ void k_scan1(const int* __restrict__ deg, int* __restrict__ csum,
                        float* __restrict__ dinv) {
  __shared__ int lds[256];
  int b = blockIdx.x, t = threadIdx.x;
  int base = b * SCAN_CHUNK + t * 8;
  int s = 0;
#pragma unroll
  for (int k = 0; k < 8; ++k) {
    int i = base + k;
    int d = (i < N_NODES) ? deg[i] : 0;
    if (i < N_NODES) dinv[i] = rsqrtf((float)d + 1.0f);
    s += d;
  }
  lds[t] = s;
  __syncthreads();
  for (int off = 128; off > 0; off >>= 1) {
    if (t < off) lds[t] += lds[t + off];
    __syncthreads();
  }
  if (t == 0) csum[b] = lds[0];
}

__global__ void k_scan3(const int* __restrict__ deg, const int* __restrict__ csum,
                        int* __restrict__ offsets) {
  __shared__ int lds[256];
  __shared__ int soff;
  int b = blockIdx.x, t = threadIdx.x;
  if (t == 0) {
    int run = 0;
    for (int i = 0; i < b; ++i) run += csum[i];
    soff = run;
  }
  int base = b * SCAN_CHUNK + t * 8;
  int v[8];
  int s = 0;
#pragma unroll
  for (int k = 0; k < 8; ++k) {
    int i = base + k;
    v[k] = (i < N_NODES) ? deg[i] : 0;
    s += v[k];
  }
  lds[t] = s;
  __syncthreads();
  int total = s;
  for (int off = 1; off < 256; off <<= 1) {
    int x = (t >= off) ? lds[t - off] : 0;
    __syncthreads();
    lds[t] += x;
    __syncthreads();
  }
  int run = lds[t] - total + soff;
#pragma unroll
  for (int k = 0; k < 8; ++k) {
    int i = base + k;
    if (i < N_NODES) offsets[i] = run;
    run += v[k];
  }
}

__global__ void k_fill(const int* __restrict__ ei, const int* __restrict__ offsets,
                       int* __restrict__ cursor, int* __restrict__ csr_row) {
  int e = blockIdx.x * blockDim.x + threadIdx.x;
  if (e < N_EDGES) {
    int r = ei[e];
    int c = ei[N_EDGES + e];
    int p = atomicAdd(&cursor[c], 1);
    csr_row[offsets[c] + p] = r;
  }
}

// ------- xw' = (x @ W1) * dinv[row], bf16 out, MFMA 16x16x32 -------
// 4 waves/block; wave = one 16-row chunk x all 128 cols. W1 staged once/block
// into LDS transposed-bf16 (Wt[n][k], stride 136: 2-way banks = free), then all
// 32 B-frags live in registers (128 VGPR) for the block lifetime -> zero LDS in
// the main loop. A-frags straight from fp32 x (16 full cachelines per instr),
// RNE->bf16 in-register. Layouts per m89/m91/m120: A[m=lane&15][k=quad*8+j],
// B[k=quad*8+j][n=lane&15], D col=lane&15 row=quad*4+reg.
__global__ __launch_bounds__(256, 2) void k_gemm_mfma(const float* __restrict__ x,
                                                      const float* __restrict__ W1,
                                                      const float* __restrict__ dinv,
                                                      ushort16* __restrict__ xw) {
  __shared__ __align__(16) unsigned short Wt[128 * 136];  // 34.8 KB
  int t = threadIdx.x;
  for (int i = t; i < 4096; i += 256) {
    float4 w4 = ((const float4*)W1)[i];
    int k = i >> 5;         // 0..127
    int n0 = (i & 31) * 4;  // 0..124
    Wt[(n0 + 0) * 136 + k] = f2bf(w4.x);
    Wt[(n0 + 1) * 136 + k] = f2bf(w4.y);
    Wt[(n0 + 2) * 136 + k] = f2bf(w4.z);
    Wt[(n0 + 3) * 136 + k] = f2bf(w4.w);
  }
  __syncthreads();

  int lane = t & 63;
  int c = lane & 15;     // col-in-tile; also row-in-chunk for the A fragment
  int quad = lane >> 4;  // 0..3
  short8 b[4][8];        // all B fragments, register-resident
#pragma unroll
  for (int kt = 0; kt < 4; ++kt)
#pragma unroll
    for (int nt = 0; nt < 8; ++nt)
      b[kt][nt] = *(const short8*)&Wt[(nt * 16 + c) * 136 + kt * 32 + quad * 8];

  int wave = blockIdx.x * 4 + (t >> 6);
  for (int chunk = wave; chunk < N_CHUNKS; chunk += GEMM_BLOCKS * 4) {
    const float* xr = x + (size_t)(chunk * 16 + c) * 128 + quad * 8;
    short8 a[4];
#pragma unroll
    for (int kt = 0; kt < 4; ++kt) {
      float4 f0 = *(const float4*)(xr + kt * 32);
      float4 f1 = *(const float4*)(xr + kt * 32 + 4);
      short8 v;
      v[0] = (short)f2bf(f0.x); v[1] = (short)f2bf(f0.y);
      v[2] = (short)f2bf(f0.z); v[3] = (short)f2bf(f0.w);
      v[4] = (short)f2bf(f1.x); v[5] = (short)f2bf(f1.y);
      v[6] = (short)f2bf(f1.z); v[7] = (short)f2bf(f1.w);
      a[kt] = v;
    }
    f32x4 acc[8];
#pragma unroll
    for (int nt = 0; nt < 8; ++nt) acc[nt] = (f32x4)(0.f);
#pragma unroll
    for (int kt = 0; kt < 4; ++kt)
#pragma unroll
      for (int nt = 0; nt < 8; ++nt)
        acc[nt] = __builtin_amdgcn_mfma_f32_16x16x32_bf16(a[kt], b[kt][nt], acc[nt], 0, 0, 0);

    int rbase = chunk * 16 + quad * 4;  // D row = quad*4 + reg
    float d0 = dinv[rbase + 0], d1 = dinv[rbase + 1];
    float d2 = dinv[rbase + 2], d3 = dinv[rbase + 3];
    unsigned short* xo = (unsigned short*)xw;
#pragma unroll
    for (int nt = 0; nt < 8; ++nt) {
      int cb = nt * 16 + c;
      xo[(size_t)(rbase + 0) * 128 + cb] = f2bf(acc[nt][0] * d0);
      xo[(size_t)(rbase + 1) * 128 + cb] = f2bf(acc[nt][1] * d1);
      xo[(size_t)(rbase + 2) * 128 + cb] = f2bf(acc[nt][2] * d2);
      xo[(size_t)(rbase + 3) * 128 + cb] = f2bf(acc[nt][3] * d3);
    }
  }
}

// ----- conv1: per-node CSR gather of bf16 xw', h = relu(dc*Σ + b1), bf16 out -----
__global__ __launch_bounds__(256) void k_conv1(const ushort16* __restrict__ xw,
                                               const int* __restrict__ csr_row,
                                               const int* __restrict__ offsets,
                                               const int* __restrict__ deg,
                                               const float* __restrict__ dinv,
                                               const float* __restrict__ b1,
                                               ushort16* __restrict__ h) {
  int lane = threadIdx.x & 63;
  int c = blockIdx.x * 4 + (threadIdx.x >> 6);  // one wave per node
  if (c >= N_NODES) return;
  float dc = dinv[c];
  const uint32* base = (const uint32*)xw;  // row = 64 uints (128 bf16)
  uint32 su = base[(size_t)c * 64 + lane];
  float acc0 = bflo(su);
  float acc1 = bfhi(su);
  int st = offsets[c], cnt = deg[c];
  int s = 0;
  for (; s + 8 <= cnt; s += 8) {  // 8 independent gathers in flight
    int r0 = csr_row[st + s + 0];
    int r1 = csr_row[st + s + 1];
    int r2 = csr_row[st + s + 2];
    int r3 = csr_row[st + s + 3];
    int r4 = csr_row[st + s + 4];
    int r5 = csr_row[st + s + 5];
    int r6 = csr_row[st + s + 6];
    int r7 = csr_row[st + s + 7];
    uint32 u0 = base[(size_t)r0 * 64 + lane];
    uint32 u1 = base[(size_t)r1 * 64 + lane];
    uint32 u2 = base[(size_t)r2 * 64 + lane];
    uint32 u3 = base[(size_t)r3 * 64 + lane];
    uint32 u4 = base[(size_t)r4 * 64 + lane];
    uint32 u5 = base[(size_t)r5 * 64 + lane];
    uint32 u6 = base[(size_t)r6 * 64 + lane];
    uint32 u7 = base[(size_t)r7 * 64 + lane];
    acc0 += ((bflo(u0) + bflo(u1)) + (bflo(u2) + bflo(u3))) +
            ((bflo(u4) + bflo(u5)) + (bflo(u6) + bflo(u7)));
    acc1 += ((bfhi(u0) + bfhi(u1)) + (bfhi(u2) + bfhi(u3))) +
            ((bfhi(u4) + bfhi(u5)) + (bfhi(u6) + bfhi(u7)));
  }
  for (; s + 2 <= cnt; s += 2) {
    int r0 = csr_row[st + s + 0];
    int r1 = csr_row[st + s + 1];
    uint32 u0 = base[(size_t)r0 * 64 + lane];
    uint32 u1 = base[(size_t)r1 * 64 + lane];
    acc0 += bflo(u0) + bflo(u1);
    acc1 += bfhi(u0) + bfhi(u1);
  }
  for (; s < cnt; ++s) {
    int r = csr_row[st + s];
    uint32 u = base[(size_t)r * 64 + lane];
    acc0 += bflo(u);
    acc1 += bfhi(u);
  }
  float2 bb = ((const float2*)b1)[lane];
  float o0 = fmaxf(acc0 * dc + bb.x, 0.f);
  float o1 = fmaxf(acc1 * dc + bb.y, 0.f);
  ((uint32*)h)[(size_t)c * 64 + lane] = bfpack(o0, o1);
}

// ----- coef[r][g] = Σ_{e from r, batch[col]=g} dinv[r]dinv[c]  (+self) -----
__global__ void k_coef_init(const int* __restrict__ batch, const float* __restrict__ dinv,
                            float* __restrict__ coef) {
  int i = blockIdx.x * blockDim.x + threadIdx.x;  // node*16+g
  if (i < N_NODES * N_GRAPHS) {
    int n = i >> 4, g = i & 15;
    float d = dinv[n];
    coef[i] = (g == batch[n]) ? d * d : 0.f;
  }
}

__global__ void k_coef_edge(const int* __restrict__ ei, const int* __restrict__ batch,
                            const float* __restrict__ dinv, float* __restrict__ coef) {
  int e = blockIdx.x * blockDim.x + threadIdx.x;
  if (e < N_EDGES) {
    int r = ei[e];
    int c = ei[N_EDGES + e];
    int g = batch[c];
    atomicAdd(&coef[r * N_GRAPHS + g], dinv[r] * dinv[c]);
  }
}

// ----- s[g][f] = Σ_r coef[r][g]*h[r][f]  (streaming bf16 h; coef in LDS) -----
__global__ __launch_bounds__(256) void k_sum(const ushort16* __restrict__ h,
                                             const float* __restrict__ coef,
                                             float* __restrict__ partials) {
  __shared__ float lds[8192];  // phase1: coef tile (16KB); phase2: wave partials (32KB)
  int t = threadIdx.x;
  int base = blockIdx.x * SUM_ROWS;

  for (int i = t; i < SUM_ROWS * 16 / 4; i += 256) {
    int gidx = base * 16 / 4 + i;
    float4 v = (gidx * 4 < N_NODES * 16) ? ((const float4*)coef)[gidx]
                                         : make_float4(0.f, 0.f, 0.f, 0.f);
    ((float4*)lds)[i] = v;
  }
  __syncthreads();

  int lane = t & 63;
  int q = t >> 6;  // wave id 0..3
  float2 acc[16];
#pragma unroll
  for (int g = 0; g < 16; ++g) acc[g] = make_float2(0.f, 0.f);

  const uint32* h2 = (const uint32*)h;
  for (int k = 0; k < SUM_ROWS / 4; ++k) {
    int lr = q + 4 * k;
    int r = base + lr;
    uint32 u = (r < N_NODES) ? h2[(size_t)r * 64 + lane] : 0u;
    float hx = bflo(u), hy = bfhi(u);
    const float4* cb = (const float4*)&lds[lr * 16];
    float4 c0 = cb[0], c1 = cb[1], c2 = cb[2], c3 = cb[3];
    acc[0].x += c0.x * hx;  acc[0].y += c0.x * hy;
    acc[1].x += c0.y * hx;  acc[1].y += c0.y * hy;
    acc[2].x += c0.z * hx;  acc[2].y += c0.z * hy;
    acc[3].x += c0.w * hx;  acc[3].y += c0.w * hy;
    acc[4].x += c1.x * hx;  acc[4].y += c1.x * hy;
    acc[5].x += c1.y * hx;  acc[5].y += c1.y * hy;
    acc[6].x += c1.z * hx;  acc[6].y += c1.z * hy;
    acc[7].x += c1.w * hx;  acc[7].y += c1.w * hy;
    acc[8].x += c2.x * hx;  acc[8].y += c2.x * hy;
    acc[9].x += c2.y * hx;  acc[9].y += c2.y * hy;
    acc[10].x += c2.z * hx; acc[10].y += c2.z * hy;
    acc[11].x += c2.w * hx; acc[11].y += c2.w * hy;
    acc[12].x += c3.x * hx; acc[12].y += c3.x * hy;
    acc[13].x += c3.y * hx; acc[13].y += c3.y * hy;
    acc[14].x += c3.z * hx; acc[14].y += c3.z * hy;
    acc[15].x += c3.w * hx; acc[15].y += c3.w * hy;
  }
  __syncthreads();
  float2* red = (float2*)lds;
#pragma unroll
  for (int g = 0; g < 16; ++g) red[(q * 16 + g) * 64 + lane] = acc[g];
  __syncthreads();
#pragma unroll
  for (int ii = 0; ii < 4; ++ii) {
    int i = t + ii * 256;
    int g = i >> 6, fp = i & 63;
    float2 sv = red[(0 * 16 + g) * 64 + fp];
    float2 s1 = red[(1 * 16 + g) * 64 + fp];
    float2 s2 = red[(2 * 16 + g) * 64 + fp];
    float2 s3 = red[(3 * 16 + g) * 64 + fp];
    sv.x += s1.x + s2.x + s3.x;
    sv.y += s1.y + s2.y + s3.y;
    ((float2*)partials)[(size_t)blockIdx.x * 1024 + g * 64 + fp] = sv;
  }
}

__global__ void k_reduce(const float* __restrict__ partials, float* __restrict__ sglob) {
  int i = blockIdx.x * blockDim.x + threadIdx.x;
  if (i < N_GRAPHS * 128) {
    float s = 0.f;
    for (int b = 0; b < SUM_NB; ++b) s += partials[(size_t)b * (N_GRAPHS * 128) + i];
    sglob[i] = s;
  }
}

// ---------------- final: counts, s@W2, mean, log_softmax ----------------
__global__ void k_final(const float* __restrict__ sglob, const int* __restrict__ batch,
                        const float* __restrict__ W2, const float* __restrict__ b2,
                        float* __restrict__ out) {
  __shared__ int bnd[N_GRAPHS + 1];
  int t = threadIdx.x;
  if (t <= N_GRAPHS) {
    if (t == N_GRAPHS) {
      bnd[t] = N_NODES;
    } else if (t == 0) {
      bnd[t] = 0;
    } else {
      int lo = 0, hi = N_NODES;
      while (lo < hi) {
        int mid = (lo + hi) >> 1;
        if (batch[mid] < t) lo = mid + 1; else hi = mid;
      }
      bnd[t] = lo;
    }
  }
  __syncthreads();
  if (t < N_GRAPHS) {
    float cnt = fmaxf((float)(bnd[t + 1] - bnd[t]), 1.0f);
    float p0 = 0.f, p1 = 0.f;
    const float* sg = sglob + t * 128;
    for (int f = 0; f < 128; ++f) {
      float sv = sg[f];
      p0 += sv * W2[f * 2 + 0];
      p1 += sv * W2[f * 2 + 1];
    }
    p0 = p0 / cnt + b2[0];
    p1 = p1 / cnt + b2[1];
    float m = fmaxf(p0, p1);
    float lse = m + logf(expf(p0 - m) + expf(p1 - m));
    out[t * 2 + 0] = p0 - lse;
    out[t * 2 + 1] = p1 - lse;
  }
}

// ---------------- launch ----------------
static inline size_t align256(size_t x) { return (x + 255) & ~(size_t)255; }

extern "C" void kernel_launch(void* const* d_in, const int* in_sizes, int n_in,
                              void* d_out, int out_size, void* d_ws, size_t ws_size,
                              hipStream_t stream) {
  (void)in_sizes; (void)n_in; (void)out_size; (void)ws_size;
  const float* x  = (const float*)d_in[0];
  const int*   ei = (const int*)d_in[1];   // [2][E]
  const int*   batch = (const int*)d_in[2];
  const float* W1 = (const float*)d_in[3];
  const float* b1 = (const float*)d_in[4];
  const float* W2 = (const float*)d_in[5];
  const float* b2 = (const float*)d_in[6];
  float* out = (float*)d_out;

  char* w = (char*)d_ws;
  size_t off = 0;
  ushort16* xw = (ushort16*)(w + off);  off = align256(off + (size_t)N_NODES * NHID * 2);
  ushort16* h  = (ushort16*)(w + off);  off = align256(off + (size_t)N_NODES * NHID * 2);
  float* coef = (float*)(w + off);      off = align256(off + (size_t)N_NODES * N_GRAPHS * 4);
  int* csr_row = (int*)(w + off);       // alias with partials (partials used after conv1)
  float* partials = (float*)(w + off);
  size_t shared_sz = (size_t)SUM_NB * N_GRAPHS * 128 * 4;
  if ((size_t)N_EDGES * 4 > shared_sz) shared_sz = (size_t)N_EDGES * 4;
  off = align256(off + shared_sz);
  float* sglob = (float*)(w + off);     off = align256(off + (size_t)N_GRAPHS * 128 * 4);
  float* dinv = (float*)(w + off);      off = align256(off + (size_t)N_NODES * 4);
  int* deg = (int*)(w + off);           off = align256(off + (size_t)N_NODES * 4);
  int* cursor = (int*)(w + off);        off = align256(off + (size_t)N_NODES * 4);
  int* offsets = (int*)(w + off);       off = align256(off + (size_t)N_NODES * 4);
  int* csum = (int*)(w + off);          off = align256(off + (size_t)NCHUNK * 4);

  k_zero2<<<(N_NODES + 255) / 256, 256, 0, stream>>>(deg, cursor);
  k_deg<<<(N_EDGES + 255) / 256, 256, 0, stream>>>(ei, deg);
  k_scan1<<<NCHUNK, 256, 0, stream>>>(deg, csum, dinv);
  k_scan3<<<NCHUNK, 256, 0, stream>>>(deg, csum, offsets);
  k_fill<<<(N_EDGES + 255) / 256, 256, 0, stream>>>(ei, offsets, cursor, csr_row);
  k_gemm_mfma<<<GEMM_BLOCKS, 256, 0, stream>>>(x, W1, dinv, xw);
  k_conv1<<<(N_NODES + 3) / 4, 256, 0, stream>>>(xw, csr_row, offsets, deg, dinv, b1, h);
  k_coef_init<<<(N_NODES * N_GRAPHS + 255) / 256, 256, 0, stream>>>(batch, dinv, coef);
  k_coef_edge<<<(N_EDGES + 255) / 256, 256, 0, stream>>>(ei, batch, dinv, coef);
  k_sum<<<SUM_NB, 256, 0, stream>>>(h, coef, partials);
  k_reduce<<<8, 256, 0, stream>>>(partials, sglob);
  k_final<<<1, 64, 0, stream>>>(sglob, batch, W2, b2, out);
}

// Round 7
// 323.415 us; speedup vs baseline: 2.9676x; 1.0136x over previous
//
#include <hip/hip_runtime.h>
#include <hip/hip_bf16.h>

#define N_NODES 100000
#define N_EDGES 800000
#define N_GRAPHS 16
#define NFEAT 128
#define NHID 128
#define NCLASS 2

#define SCAN_CHUNK 2048
#define NCHUNK ((N_NODES + SCAN_CHUNK - 1) / SCAN_CHUNK)  // 49

#define SUM_ROWS 256
#define SUM_NB ((N_NODES + SUM_ROWS - 1) / SUM_ROWS)  // 391

#define GEMM_BLOCKS 512
#define N_CHUNKS (N_NODES / 16)  // 6250 exact

#define FILL_BINS 8
#define FILL_SLICES 128
#define FILL_BIN_W (N_NODES / FILL_BINS)        // 12500
#define FILL_SLICE_E (N_EDGES / FILL_SLICES)    // 6250

typedef unsigned int uint32;
typedef unsigned short ushort16;
typedef __attribute__((ext_vector_type(8))) short short8;
typedef __attribute__((ext_vector_type(4))) float f32x4;

// ---- bf16 helpers (manual RNE; low ushort = first element of the pair) ----
__device__ __forceinline__ unsigned short f2bf(float f) {
  unsigned u = __float_as_uint(f);
  unsigned r = (u + 0x7fffu + ((u >> 16) & 1u)) >> 16;
  return (unsigned short)r;
}
__device__ __forceinline__ uint32 bfpack(float a, float b) {
  return (uint32)f2bf(a) | ((uint32)f2bf(b) << 16);
}
__device__ __forceinline__ float bflo(uint32 u) { return __uint_as_float(u << 16); }
__device__ __forceinline__ float bfhi(uint32 u) { return __uint_as_float(u & 0xffff0000u); }

// ---------------- utility ----------------
__global__ void k_zero(int* __restrict__ a) {
  int i = blockIdx.x * blockDim.x + threadIdx.x;
  if (i < N_NODES) a[i] = 0;
}

// in-degree from edge targets (self-loop handled as +1 in dinv)
__global__ void k_deg(const int* __restrict__ ei, int* __restrict__ deg) {
  int e = blockIdx.x * blockDim.x + threadIdx.x;
  if (e < N_EDGES) atomicAdd(&deg[ei[N_EDGES + e]], 1);
}

// ---------------- scan of deg -> offsets (+ dinv fused) ----------------
__global__ void k_scan1(const int* __restrict__ deg, int* __restrict__ csum,
                        float* __restrict__ dinv) {
  __shared__ int lds[256];
  int b = blockIdx.x, t = threadIdx.x;
  int base = b * SCAN_CHUNK + t * 8;
  int s = 0;
#pragma unroll
  for (int k = 0; k < 8; ++k) {
    int i = base + k;
    int d = (i < N_NODES) ? deg[i] : 0;
    if (i < N_NODES) dinv[i] = rsqrtf((float)d + 1.0f);
    s += d;
  }
  lds[t] = s;
  __syncthreads();
  for (int off = 128; off > 0; off >>= 1) {
    if (t < off) lds[t] += lds[t + off];
    __syncthreads();
  }
  if (t == 0) csum[b] = lds[0];
}

// writes offsets AND cursor (cursor starts at offsets; k_fill atomics on it)
__global__ void k_scan3(const int* __restrict__ deg, const int* __restrict__ csum,
                        int* __restrict__ offsets, int* __restrict__ cursor) {
  __shared__ int lds[256];
  __shared__ int soff;
  int b = blockIdx.x, t = threadIdx.x;
  if (t == 0) {
    int run = 0;
    for (int i = 0; i < b; ++i) run += csum[i];
    soff = run;
  }
  int base = b * SCAN_CHUNK + t * 8;
  int v[8];
  int s = 0;
#pragma unroll
  for (int k = 0; k < 8; ++k) {
    int i = base + k;
    v[k] = (i < N_NODES) ? deg[i] : 0;
    s += v[k];
  }
  lds[t] = s;
  __syncthreads();
  int total = s;
  for (int off = 1; off < 256; off <<= 1) {
    int x = (t >= off) ? lds[t - off] : 0;
    __syncthreads();
    lds[t] += x;
    __syncthreads();
  }
  int run = lds[t] - total + soff;
#pragma unroll
  for (int k = 0; k < 8; ++k) {
    int i = base + k;
    if (i < N_NODES) { offsets[i] = run; cursor[i] = run; }
    run += v[k];
  }
}

// XCD-binned CSR fill: block (bin = blockIdx%8, slice = blockIdx/8) scans its
// slice of the edge list and only handles targets in its bin's 12500-node
// range. With blockIdx%8 ~ XCD, each csr_row/cursor line has a single-XCD
// writer -> no cross-XCD dirty-line ping-pong (R6: 58MB HBM write for a
// 3.2MB array, 18x amplification, ~52us of the 57us).
__global__ __launch_bounds__(256) void k_fill(const int* __restrict__ ei,
                                              int* __restrict__ cursor,
                                              int* __restrict__ csr_row) {
  int bin = blockIdx.x & (FILL_BINS - 1);
  int slice = blockIdx.x >> 3;
  int lo = bin * FILL_BIN_W;
  int hi = lo + FILL_BIN_W;
  int e0 = slice * FILL_SLICE_E;
  int e1 = e0 + FILL_SLICE_E;
  for (int e = e0 + threadIdx.x; e < e1; e += 256) {
    int c = ei[N_EDGES + e];
    if (c >= lo && c < hi) {
      int r = ei[e];
      int p = atomicAdd(&cursor[c], 1);
      csr_row[p] = r;
    }
  }
}

// ------- xw' = (x @ W1) * dinv[row], bf16 out, MFMA 16x16x32 -------
__global__ __launch_bounds__(256, 2) void k_gemm_mfma(const float* __restrict__ x,
                                                      const float* __restrict__ W1,
                                                      const float* __restrict__ dinv,
                                                      ushort16* __restrict__ xw) {
  __shared__ __align__(16) unsigned short Wt[128 * 136];  // 34.8 KB
  int t = threadIdx.x;
  for (int i = t; i < 4096; i += 256) {
    float4 w4 = ((const float4*)W1)[i];
    int k = i >> 5;         // 0..127
    int n0 = (i & 31) * 4;  // 0..124
    Wt[(n0 + 0) * 136 + k] = f2bf(w4.x);
    Wt[(n0 + 1) * 136 + k] = f2bf(w4.y);
    Wt[(n0 + 2) * 136 + k] = f2bf(w4.z);
    Wt[(n0 + 3) * 136 + k] = f2bf(w4.w);
  }
  __syncthreads();

  int lane = t & 63;
  int c = lane & 15;     // col-in-tile; also row-in-chunk for the A fragment
  int quad = lane >> 4;  // 0..3
  short8 b[4][8];        // all B fragments, register-resident
#pragma unroll
  for (int kt = 0; kt < 4; ++kt)
#pragma unroll
    for (int nt = 0; nt < 8; ++nt)
      b[kt][nt] = *(const short8*)&Wt[(nt * 16 + c) * 136 + kt * 32 + quad * 8];

  int wave = blockIdx.x * 4 + (t >> 6);
  for (int chunk = wave; chunk < N_CHUNKS; chunk += GEMM_BLOCKS * 4) {
    const float* xr = x + (size_t)(chunk * 16 + c) * 128 + quad * 8;
    short8 a[4];
#pragma unroll
    for (int kt = 0; kt < 4; ++kt) {
      float4 f0 = *(const float4*)(xr + kt * 32);
      float4 f1 = *(const float4*)(xr + kt * 32 + 4);
      short8 v;
      v[0] = (short)f2bf(f0.x); v[1] = (short)f2bf(f0.y);
      v[2] = (short)f2bf(f0.z); v[3] = (short)f2bf(f0.w);
      v[4] = (short)f2bf(f1.x); v[5] = (short)f2bf(f1.y);
      v[6] = (short)f2bf(f1.z); v[7] = (short)f2bf(f1.w);
      a[kt] = v;
    }
    f32x4 acc[8];
#pragma unroll
    for (int nt = 0; nt < 8; ++nt) acc[nt] = (f32x4)(0.f);
#pragma unroll
    for (int kt = 0; kt < 4; ++kt)
#pragma unroll
      for (int nt = 0; nt < 8; ++nt)
        acc[nt] = __builtin_amdgcn_mfma_f32_16x16x32_bf16(a[kt], b[kt][nt], acc[nt], 0, 0, 0);

    int rbase = chunk * 16 + quad * 4;  // D row = quad*4 + reg
    float d0 = dinv[rbase + 0], d1 = dinv[rbase + 1];
    float d2 = dinv[rbase + 2], d3 = dinv[rbase + 3];
    unsigned short* xo = (unsigned short*)xw;
#pragma unroll
    for (int nt = 0; nt < 8; ++nt) {
      int cb = nt * 16 + c;
      xo[(size_t)(rbase + 0) * 128 + cb] = f2bf(acc[nt][0] * d0);
      xo[(size_t)(rbase + 1) * 128 + cb] = f2bf(acc[nt][1] * d1);
      xo[(size_t)(rbase + 2) * 128 + cb] = f2bf(acc[nt][2] * d2);
      xo[(size_t)(rbase + 3) * 128 + cb] = f2bf(acc[nt][3] * d3);
    }
  }
}

// ----- conv1: per-node CSR gather of bf16 xw', h = relu(dc*Σ + b1), bf16 out -----
__global__ __launch_bounds__(256) void k_conv1(const ushort16* __restrict__ xw,
                                               const int* __restrict__ csr_row,
                                               const int* __restrict__ offsets,
                                               const int* __restrict__ deg,
                                               const float* __restrict__ dinv,
                                               const float* __restrict__ b1,
                                               ushort16* __restrict__ h) {
  int lane = threadIdx.x & 63;
  int c = blockIdx.x * 4 + (threadIdx.x >> 6);  // one wave per node
  if (c >= N_NODES) return;
  float dc = dinv[c];
  const uint32* base = (const uint32*)xw;  // row = 64 uints (128 bf16)
  uint32 su = base[(size_t)c * 64 + lane];
  float acc0 = bflo(su);
  float acc1 = bfhi(su);
  int st = offsets[c], cnt = deg[c];
  int s = 0;
  for (; s + 8 <= cnt; s += 8) {  // 8 independent gathers in flight
    int r0 = csr_row[st + s + 0];
    int r1 = csr_row[st + s + 1];
    int r2 = csr_row[st + s + 2];
    int r3 = csr_row[st + s + 3];
    int r4 = csr_row[st + s + 4];
    int r5 = csr_row[st + s + 5];
    int r6 = csr_row[st + s + 6];
    int r7 = csr_row[st + s + 7];
    uint32 u0 = base[(size_t)r0 * 64 + lane];
    uint32 u1 = base[(size_t)r1 * 64 + lane];
    uint32 u2 = base[(size_t)r2 * 64 + lane];
    uint32 u3 = base[(size_t)r3 * 64 + lane];
    uint32 u4 = base[(size_t)r4 * 64 + lane];
    uint32 u5 = base[(size_t)r5 * 64 + lane];
    uint32 u6 = base[(size_t)r6 * 64 + lane];
    uint32 u7 = base[(size_t)r7 * 64 + lane];
    acc0 += ((bflo(u0) + bflo(u1)) + (bflo(u2) + bflo(u3))) +
            ((bflo(u4) + bflo(u5)) + (bflo(u6) + bflo(u7)));
    acc1 += ((bfhi(u0) + bfhi(u1)) + (bfhi(u2) + bfhi(u3))) +
            ((bfhi(u4) + bfhi(u5)) + (bfhi(u6) + bfhi(u7)));
  }
  for (; s + 2 <= cnt; s += 2) {
    int r0 = csr_row[st + s + 0];
    int r1 = csr_row[st + s + 1];
    uint32 u0 = base[(size_t)r0 * 64 + lane];
    uint32 u1 = base[(size_t)r1 * 64 + lane];
    acc0 += bflo(u0) + bflo(u1);
    acc1 += bfhi(u0) + bfhi(u1);
  }
  for (; s < cnt; ++s) {
    int r = csr_row[st + s];
    uint32 u = base[(size_t)r * 64 + lane];
    acc0 += bflo(u);
    acc1 += bfhi(u);
  }
  float2 bb = ((const float2*)b1)[lane];
  float o0 = fmaxf(acc0 * dc + bb.x, 0.f);
  float o1 = fmaxf(acc1 * dc + bb.y, 0.f);
  ((uint32*)h)[(size_t)c * 64 + lane] = bfpack(o0, o1);
}

// ----- coef[r][g] = Σ_{e from r, batch[col]=g} dinv[r]dinv[c]  (+self) -----
__global__ void k_coef_init(const int* __restrict__ batch, const float* __restrict__ dinv,
                            float* __restrict__ coef) {
  int i = blockIdx.x * blockDim.x + threadIdx.x;  // node*16+g
  if (i < N_NODES * N_GRAPHS) {
    int n = i >> 4, g = i & 15;
    float d = dinv[n];
    coef[i] = (g == batch[n]) ? d * d : 0.f;
  }
}

__global__ void k_coef_edge(const int* __restrict__ ei, const int* __restrict__ batch,
                            const float* __restrict__ dinv, float* __restrict__ coef) {
  int e = blockIdx.x * blockDim.x + threadIdx.x;
  if (e < N_EDGES) {
    int r = ei[e];
    int c = ei[N_EDGES + e];
    int g = batch[c];
    atomicAdd(&coef[r * N_GRAPHS + g], dinv[r] * dinv[c]);
  }
}

// ----- s[g][f] = Σ_r coef[r][g]*h[r][f]  (streaming bf16 h; coef in LDS) -----
__global__ __launch_bounds__(256) void k_sum(const ushort16* __restrict__ h,
                                             const float* __restrict__ coef,
                                             float* __restrict__ partials) {
  __shared__ float lds[8192];  // phase1: coef tile (16KB); phase2: wave partials (32KB)
  int t = threadIdx.x;
  int base = blockIdx.x * SUM_ROWS;

  for (int i = t; i < SUM_ROWS * 16 / 4; i += 256) {
    int gidx = base * 16 / 4 + i;
    float4 v = (gidx * 4 < N_NODES * 16) ? ((const float4*)coef)[gidx]
                                         : make_float4(0.f, 0.f, 0.f, 0.f);
    ((float4*)lds)[i] = v;
  }
  __syncthreads();

  int lane = t & 63;
  int q = t >> 6;  // wave id 0..3
  float2 acc[16];
#pragma unroll
  for (int g = 0; g < 16; ++g) acc[g] = make_float2(0.f, 0.f);

  const uint32* h2 = (const uint32*)h;
  for (int k = 0; k < SUM_ROWS / 4; ++k) {
    int lr = q + 4 * k;
    int r = base + lr;
    uint32 u = (r < N_NODES) ? h2[(size_t)r * 64 + lane] : 0u;
    float hx = bflo(u), hy = bfhi(u);
    const float4* cb = (const float4*)&lds[lr * 16];
    float4 c0 = cb[0], c1 = cb[1], c2 = cb[2], c3 = cb[3];
    acc[0].x += c0.x * hx;  acc[0].y += c0.x * hy;
    acc[1].x += c0.y * hx;  acc[1].y += c0.y * hy;
    acc[2].x += c0.z * hx;  acc[2].y += c0.z * hy;
    acc[3].x += c0.w * hx;  acc[3].y += c0.w * hy;
    acc[4].x += c1.x * hx;  acc[4].y += c1.x * hy;
    acc[5].x += c1.y * hx;  acc[5].y += c1.y * hy;
    acc[6].x += c1.z * hx;  acc[6].y += c1.z * hy;
    acc[7].x += c1.w * hx;  acc[7].y += c1.w * hy;
    acc[8].x += c2.x * hx;  acc[8].y += c2.x * hy;
    acc[9].x += c2.y * hx;  acc[9].y += c2.y * hy;
    acc[10].x += c2.z * hx; acc[10].y += c2.z * hy;
    acc[11].x += c2.w * hx; acc[11].y += c2.w * hy;
    acc[12].x += c3.x * hx; acc[12].y += c3.x * hy;
    acc[13].x += c3.y * hx; acc[13].y += c3.y * hy;
    acc[14].x += c3.z * hx; acc[14].y += c3.z * hy;
    acc[15].x += c3.w * hx; acc[15].y += c3.w * hy;
  }
  __syncthreads();
  float2* red = (float2*)lds;
#pragma unroll
  for (int g = 0; g < 16; ++g) red[(q * 16 + g) * 64 + lane] = acc[g];
  __syncthreads();
#pragma unroll
  for (int ii = 0; ii < 4; ++ii) {
    int i = t + ii * 256;
    int g = i >> 6, fp = i & 63;
    float2 sv = red[(0 * 16 + g) * 64 + fp];
    float2 s1 = red[(1 * 16 + g) * 64 + fp];
    float2 s2 = red[(2 * 16 + g) * 64 + fp];
    float2 s3 = red[(3 * 16 + g) * 64 + fp];
    sv.x += s1.x + s2.x + s3.x;
    sv.y += s1.y + s2.y + s3.y;
    ((float2*)partials)[(size_t)blockIdx.x * 1024 + g * 64 + fp] = sv;
  }
}

__global__ void k_reduce(const float* __restrict__ partials, float* __restrict__ sglob) {
  int i = blockIdx.x * blockDim.x + threadIdx.x;
  if (i < N_GRAPHS * 128) {
    float s = 0.f;
    for (int b = 0; b < SUM_NB; ++b) s += partials[(size_t)b * (N_GRAPHS * 128) + i];
    sglob[i] = s;
  }
}

// ---------------- final: counts, s@W2, mean, log_softmax ----------------
__global__ void k_final(const float* __restrict__ sglob, const int* __restrict__ batch,
                        const float* __restrict__ W2, const float* __restrict__ b2,
                        float* __restrict__ out) {
  __shared__ int bnd[N_GRAPHS + 1];
  int t = threadIdx.x;
  if (t <= N_GRAPHS) {
    if (t == N_GRAPHS) {
      bnd[t] = N_NODES;
    } else if (t == 0) {
      bnd[t] = 0;
    } else {
      int lo = 0, hi = N_NODES;
      while (lo < hi) {
        int mid = (lo + hi) >> 1;
        if (batch[mid] < t) lo = mid + 1; else hi = mid;
      }
      bnd[t] = lo;
    }
  }
  __syncthreads();
  if (t < N_GRAPHS) {
    float cnt = fmaxf((float)(bnd[t + 1] - bnd[t]), 1.0f);
    float p0 = 0.f, p1 = 0.f;
    const float* sg = sglob + t * 128;
    for (int f = 0; f < 128; ++f) {
      float sv = sg[f];
      p0 += sv * W2[f * 2 + 0];
      p1 += sv * W2[f * 2 + 1];
    }
    p0 = p0 / cnt + b2[0];
    p1 = p1 / cnt + b2[1];
    float m = fmaxf(p0, p1);
    float lse = m + logf(expf(p0 - m) + expf(p1 - m));
    out[t * 2 + 0] = p0 - lse;
    out[t * 2 + 1] = p1 - lse;
  }
}

// ---------------- launch ----------------
static inline size_t align256(size_t x) { return (x + 255) & ~(size_t)255; }

extern "C" void kernel_launch(void* const* d_in, const int* in_sizes, int n_in,
                              void* d_out, int out_size, void* d_ws, size_t ws_size,
                              hipStream_t stream) {
  (void)in_sizes; (void)n_in; (void)out_size; (void)ws_size;
  const float* x  = (const float*)d_in[0];
  const int*   ei = (const int*)d_in[1];   // [2][E]
  const int*   batch = (const int*)d_in[2];
  const float* W1 = (const float*)d_in[3];
  const float* b1 = (const float*)d_in[4];
  const float* W2 = (const float*)d_in[5];
  const float* b2 = (const float*)d_in[6];
  float* out = (float*)d_out;

  char* w = (char*)d_ws;
  size_t off = 0;
  ushort16* xw = (ushort16*)(w + off);  off = align256(off + (size_t)N_NODES * NHID * 2);
  ushort16* h  = (ushort16*)(w + off);  off = align256(off + (size_t)N_NODES * NHID * 2);
  float* coef = (float*)(w + off);      off = align256(off + (size_t)N_NODES * N_GRAPHS * 4);
  int* csr_row = (int*)(w + off);       // alias with partials (partials used after conv1)
  float* partials = (float*)(w + off);
  size_t shared_sz = (size_t)SUM_NB * N_GRAPHS * 128 * 4;
  if ((size_t)N_EDGES * 4 > shared_sz) shared_sz = (size_t)N_EDGES * 4;
  off = align256(off + shared_sz);
  float* sglob = (float*)(w + off);     off = align256(off + (size_t)N_GRAPHS * 128 * 4);
  float* dinv = (float*)(w + off);      off = align256(off + (size_t)N_NODES * 4);
  int* deg = (int*)(w + off);           off = align256(off + (size_t)N_NODES * 4);
  int* cursor = (int*)(w + off);        off = align256(off + (size_t)N_NODES * 4);
  int* offsets = (int*)(w + off);       off = align256(off + (size_t)N_NODES * 4);
  int* csum = (int*)(w + off);          off = align256(off + (size_t)NCHUNK * 4);

  k_zero<<<(N_NODES + 255) / 256, 256, 0, stream>>>(deg);
  k_deg<<<(N_EDGES + 255) / 256, 256, 0, stream>>>(ei, deg);
  k_scan1<<<NCHUNK, 256, 0, stream>>>(deg, csum, dinv);
  k_scan3<<<NCHUNK, 256, 0, stream>>>(deg, csum, offsets, cursor);
  k_fill<<<FILL_BINS * FILL_SLICES, 256, 0, stream>>>(ei, cursor, csr_row);
  k_gemm_mfma<<<GEMM_BLOCKS, 256, 0, stream>>>(x, W1, dinv, xw);
  k_conv1<<<(N_NODES + 3) / 4, 256, 0, stream>>>(xw, csr_row, offsets, deg, dinv, b1, h);
  k_coef_init<<<(N_NODES * N_GRAPHS + 255) / 256, 256, 0, stream>>>(batch, dinv, coef);
  k_coef_edge<<<(N_EDGES + 255) / 256, 256, 0, stream>>>(ei, batch, dinv, coef);
  k_sum<<<SUM_NB, 256, 0, stream>>>(h, coef, partials);
  k_reduce<<<8, 256, 0, stream>>>(partials, sglob);
  k_final<<<1, 64, 0, stream>>>(sglob, batch, W2, b2, out);
}